// Round 1
// baseline (2041.006 us; speedup 1.0000x reference)
//
#include <hip/hip_runtime.h>
#include <math.h>

#define BD 8
#define CD 256
#define ND 4096
#define DA 64

// ---------------------------------------------------------------------------
// K1: generic 1x1-conv transpose-out GEMM.
// out[(b*N + n)*D + d] = sum_c x[b*C*N + c*N + n] * W[d*C + c]
// grid (N/64, D/64, B), block 256. 64x64 tile, 4x4 micro.
// ---------------------------------------------------------------------------
__global__ __launch_bounds__(256) void k_qkv(const float* __restrict__ x,
                                             const float* __restrict__ W,
                                             float* __restrict__ out, int D) {
  const int n0 = blockIdx.x * 64;
  const int d0 = blockIdx.y * 64;
  const int b  = blockIdx.z;
  __shared__ float Xs[16][68];  // [c][n]
  __shared__ float Ws[16][68];  // [c][d]
  const int tid = threadIdx.x;
  const int tx = tid & 15, ty = tid >> 4;
  float acc[4][4] = {};  // [i=n][j=d]
  const float* xb = x + (size_t)b * CD * ND + n0;
  for (int c0 = 0; c0 < CD; c0 += 16) {
    {
      int kk = tid >> 4, nn4 = (tid & 15) * 4;
      *(float4*)&Xs[kk][nn4] = *(const float4*)&xb[(size_t)(c0 + kk) * ND + nn4];
      int dd = tid >> 2, kc = (tid & 3) * 4;
      float4 w4 = *(const float4*)&W[(size_t)(d0 + dd) * CD + c0 + kc];
      Ws[kc + 0][dd] = w4.x; Ws[kc + 1][dd] = w4.y;
      Ws[kc + 2][dd] = w4.z; Ws[kc + 3][dd] = w4.w;
    }
    __syncthreads();
#pragma unroll
    for (int kk = 0; kk < 16; ++kk) {
      float4 a4 = *(const float4*)&Xs[kk][ty * 4];
      float4 b4 = *(const float4*)&Ws[kk][tx * 4];
      float a[4] = {a4.x, a4.y, a4.z, a4.w};
      float bb[4] = {b4.x, b4.y, b4.z, b4.w};
#pragma unroll
      for (int i = 0; i < 4; ++i)
#pragma unroll
        for (int j = 0; j < 4; ++j) acc[i][j] += a[i] * bb[j];
    }
    __syncthreads();
  }
#pragma unroll
  for (int i = 0; i < 4; ++i) {
    float4 r = make_float4(acc[i][0], acc[i][1], acc[i][2], acc[i][3]);
    *(float4*)&out[((size_t)b * ND + n0 + ty * 4 + i) * D + d0 + tx * 4] = r;
  }
}

// ---------------------------------------------------------------------------
// K2: column softmax stats. For each column m: M[m]=max_n e[n,m],
// D[m]=sum_n exp(e-M). e[n,m] = sum_d q[b,n,d]*kT[b,m,d].
// grid (N/64 m-tiles, B), block 256.
// ---------------------------------------------------------------------------
__global__ __launch_bounds__(256) void k_colstats(const float* __restrict__ q,
                                                  const float* __restrict__ kT,
                                                  float* __restrict__ Mcol,
                                                  float* __restrict__ Dcol) {
  const int m0 = blockIdx.x * 64;
  const int b  = blockIdx.y;
  __shared__ float Ks[64][68];
  __shared__ float Qs[64][68];
  __shared__ float red[16][68];
  __shared__ float Mx[64], Dsum[64], newMs[64], scaleS[64];
  const int tid = threadIdx.x;
  const int tx = tid & 15, ty = tid >> 4;
#pragma unroll
  for (int l = 0; l < 4; ++l) {
    int e = tid + l * 256;
    int mm = e >> 4, d4 = (e & 15) * 4;
    *(float4*)&Ks[mm][d4] = *(const float4*)&kT[((size_t)b * ND + m0 + mm) * DA + d4];
  }
  if (tid < 64) { Mx[tid] = -INFINITY; Dsum[tid] = 0.f; }
  __syncthreads();
  for (int n0 = 0; n0 < ND; n0 += 64) {
#pragma unroll
    for (int l = 0; l < 4; ++l) {
      int e = tid + l * 256;
      int nn = e >> 4, d4 = (e & 15) * 4;
      *(float4*)&Qs[nn][d4] = *(const float4*)&q[((size_t)b * ND + n0 + nn) * DA + d4];
    }
    __syncthreads();
    float acc[4][4] = {};  // [i=n][j=m]
#pragma unroll
    for (int d = 0; d < 64; d += 4) {
      float4 a4[4], b4[4];
#pragma unroll
      for (int i = 0; i < 4; ++i) a4[i] = *(const float4*)&Qs[ty * 4 + i][d];
#pragma unroll
      for (int j = 0; j < 4; ++j) b4[j] = *(const float4*)&Ks[tx * 4 + j][d];
#pragma unroll
      for (int i = 0; i < 4; ++i)
#pragma unroll
        for (int j = 0; j < 4; ++j)
          acc[i][j] += a4[i].x * b4[j].x + a4[i].y * b4[j].y +
                       a4[i].z * b4[j].z + a4[i].w * b4[j].w;
    }
#pragma unroll
    for (int j = 0; j < 4; ++j)
      red[ty][tx * 4 + j] =
          fmaxf(fmaxf(acc[0][j], acc[1][j]), fmaxf(acc[2][j], acc[3][j]));
    __syncthreads();
    if (tid < 64) {
      float t = red[0][tid];
#pragma unroll
      for (int g = 1; g < 16; ++g) t = fmaxf(t, red[g][tid]);
      float oM = Mx[tid];
      float nM = fmaxf(oM, t);
      newMs[tid]  = nM;
      scaleS[tid] = expf(oM - nM);  // exp(-inf)=0 on first tile
    }
    __syncthreads();
#pragma unroll
    for (int j = 0; j < 4; ++j) {
      float nM = newMs[tx * 4 + j];
      red[ty][tx * 4 + j] = expf(acc[0][j] - nM) + expf(acc[1][j] - nM) +
                            expf(acc[2][j] - nM) + expf(acc[3][j] - nM);
    }
    __syncthreads();
    if (tid < 64) {
      float s = 0.f;
#pragma unroll
      for (int g = 0; g < 16; ++g) s += red[g][tid];
      Dsum[tid] = Dsum[tid] * scaleS[tid] + s;
      Mx[tid]   = newMs[tid];
    }
    __syncthreads();
  }
  if (tid < 64) {
    Mcol[(size_t)b * ND + m0 + tid] = Mx[tid];
    Dcol[(size_t)b * ND + m0 + tid] = Dsum[tid];
  }
}

// ---------------------------------------------------------------------------
// K3: per n-tile: recompute e, P = exp(e-M)/D, S[n] += rowsum(P),
// O[n,c] += P·V. fsa[b,c,n] = O[n,c] / (1e-9 + S[n]).
// grid (N/64 n-tiles, B), block 256.
// ---------------------------------------------------------------------------
__global__ __launch_bounds__(256) void k_attn(const float* __restrict__ q,
                                              const float* __restrict__ kT,
                                              const float* __restrict__ v,
                                              const float* __restrict__ Mcol,
                                              const float* __restrict__ Dcol,
                                              float* __restrict__ fsa) {
  const int n0 = blockIdx.x * 64;
  const int b  = blockIdx.y;
  __shared__ float Qs[64][68];   // [n][d], resident
  __shared__ float KV[64][68];   // Ks tile, then V quarters
  __shared__ float PsT[64][68];  // P^T [m][n]; reused as transpose buf in epilogue
  __shared__ float red[16][68];
  __shared__ float Md[64], Dr[64], Sacc[64];
  const int tid = threadIdx.x;
  const int tx = tid & 15, ty = tid >> 4;
#pragma unroll
  for (int l = 0; l < 4; ++l) {
    int e = tid + l * 256;
    int nn = e >> 4, d4 = (e & 15) * 4;
    *(float4*)&Qs[nn][d4] = *(const float4*)&q[((size_t)b * ND + n0 + nn) * DA + d4];
  }
  if (tid < 64) Sacc[tid] = 0.f;
  float O[4][4][4] = {};  // [quarter][i=n][j=c]
  for (int m0 = 0; m0 < ND; m0 += 64) {
#pragma unroll
    for (int l = 0; l < 4; ++l) {
      int e = tid + l * 256;
      int mm = e >> 4, d4 = (e & 15) * 4;
      *(float4*)&KV[mm][d4] = *(const float4*)&kT[((size_t)b * ND + m0 + mm) * DA + d4];
    }
    if (tid < 64) {
      Md[tid] = Mcol[(size_t)b * ND + m0 + tid];
      Dr[tid] = 1.0f / Dcol[(size_t)b * ND + m0 + tid];
    }
    __syncthreads();
    float acc[4][4] = {};  // [i=n][j=m]
#pragma unroll
    for (int d = 0; d < 64; d += 4) {
      float4 a4[4], b4[4];
#pragma unroll
      for (int i = 0; i < 4; ++i) a4[i] = *(const float4*)&Qs[ty * 4 + i][d];
#pragma unroll
      for (int j = 0; j < 4; ++j) b4[j] = *(const float4*)&KV[tx * 4 + j][d];
#pragma unroll
      for (int i = 0; i < 4; ++i)
#pragma unroll
        for (int j = 0; j < 4; ++j)
          acc[i][j] += a4[i].x * b4[j].x + a4[i].y * b4[j].y +
                       a4[i].z * b4[j].z + a4[i].w * b4[j].w;
    }
    float rs[4] = {0.f, 0.f, 0.f, 0.f};
#pragma unroll
    for (int j = 0; j < 4; ++j) {
      int m = tx * 4 + j;
      float md = Md[m], dr = Dr[m];
#pragma unroll
      for (int i = 0; i < 4; ++i) {
        float p = expf(acc[i][j] - md) * dr;
        PsT[m][ty * 4 + i] = p;
        rs[i] += p;
      }
    }
#pragma unroll
    for (int i = 0; i < 4; ++i) red[tx][ty * 4 + i] = rs[i];
    __syncthreads();  // PsT + red ready; KV (Ks) free for reuse
    if (tid < 64) {
      float s = 0.f;
#pragma unroll
      for (int g = 0; g < 16; ++g) s += red[g][tid];
      Sacc[tid] += s;
    }
#pragma unroll
    for (int qc = 0; qc < 4; ++qc) {
#pragma unroll
      for (int l = 0; l < 4; ++l) {
        int e = tid + l * 256;
        int mm = e >> 4, c4 = (e & 15) * 4;
        *(float4*)&KV[mm][c4] =
            *(const float4*)&v[((size_t)b * ND + m0 + mm) * CD + qc * 64 + c4];
      }
      __syncthreads();
#pragma unroll
      for (int mm = 0; mm < 64; ++mm) {
        float4 a4 = *(const float4*)&PsT[mm][ty * 4];
        float4 b4 = *(const float4*)&KV[mm][tx * 4];
        float a[4] = {a4.x, a4.y, a4.z, a4.w};
        float bb[4] = {b4.x, b4.y, b4.z, b4.w};
#pragma unroll
        for (int i = 0; i < 4; ++i)
#pragma unroll
          for (int j = 0; j < 4; ++j) O[qc][i][j] += a[i] * bb[j];
      }
      __syncthreads();
    }
  }
  // epilogue: scale by 1/(1e-9+S[n]) and store transposed to fsa[b,c,n]
  float rsc[4];
#pragma unroll
  for (int i = 0; i < 4; ++i) rsc[i] = 1.0f / (1e-9f + Sacc[ty * 4 + i]);
#pragma unroll
  for (int qc = 0; qc < 4; ++qc) {
#pragma unroll
    for (int i = 0; i < 4; ++i)
#pragma unroll
      for (int j = 0; j < 4; ++j)
        PsT[tx * 4 + j][ty * 4 + i] = O[qc][i][j] * rsc[i];
    __syncthreads();
#pragma unroll
    for (int l = 0; l < 4; ++l) {
      int e = tid + l * 256;
      int cc = e >> 4, n4 = (e & 15) * 4;
      *(float4*)&fsa[((size_t)b * CD + qc * 64 + cc) * ND + n0 + n4] =
          *(const float4*)&PsT[cc][n4];
    }
    __syncthreads();
  }
}

// ---------------------------------------------------------------------------
// K4: h[b,d,n] = sum_c (x-fsa)[b,c,n]*Wp[d,c]; out = relu(BN(h)) + x.
// grid (N/64, C/64, B), block 256. acc[i=d][j=n] so stores coalesce along n.
// ---------------------------------------------------------------------------
__global__ __launch_bounds__(256) void k_final(const float* __restrict__ x,
                                               const float* __restrict__ fsa,
                                               const float* __restrict__ Wp,
                                               const float* __restrict__ gamma,
                                               const float* __restrict__ beta,
                                               const float* __restrict__ mean,
                                               const float* __restrict__ var,
                                               float* __restrict__ out) {
  const int n0 = blockIdx.x * 64;
  const int d0 = blockIdx.y * 64;
  const int b  = blockIdx.z;
  __shared__ float Ys[16][68];  // [c][n]
  __shared__ float Ws[16][68];  // [c][d]
  const int tid = threadIdx.x;
  const int tx = tid & 15, ty = tid >> 4;
  float acc[4][4] = {};  // [i=d][j=n]
  const size_t xoff = (size_t)b * CD * ND + n0;
  for (int c0 = 0; c0 < CD; c0 += 16) {
    {
      int kk = tid >> 4, nn4 = (tid & 15) * 4;
      size_t gi = xoff + (size_t)(c0 + kk) * ND + nn4;
      float4 xv = *(const float4*)&x[gi];
      float4 fv = *(const float4*)&fsa[gi];
      float4 yv = make_float4(xv.x - fv.x, xv.y - fv.y, xv.z - fv.z, xv.w - fv.w);
      *(float4*)&Ys[kk][nn4] = yv;
      int dd = tid >> 2, kc = (tid & 3) * 4;
      float4 w4 = *(const float4*)&Wp[(size_t)(d0 + dd) * CD + c0 + kc];
      Ws[kc + 0][dd] = w4.x; Ws[kc + 1][dd] = w4.y;
      Ws[kc + 2][dd] = w4.z; Ws[kc + 3][dd] = w4.w;
    }
    __syncthreads();
#pragma unroll
    for (int kk = 0; kk < 16; ++kk) {
      float4 a4 = *(const float4*)&Ws[kk][ty * 4];  // d
      float4 b4 = *(const float4*)&Ys[kk][tx * 4];  // n
      float a[4] = {a4.x, a4.y, a4.z, a4.w};
      float bb[4] = {b4.x, b4.y, b4.z, b4.w};
#pragma unroll
      for (int i = 0; i < 4; ++i)
#pragma unroll
        for (int j = 0; j < 4; ++j) acc[i][j] += a[i] * bb[j];
    }
    __syncthreads();
  }
#pragma unroll
  for (int i = 0; i < 4; ++i) {
    int d = d0 + ty * 4 + i;
    float inv  = gamma[d] / sqrtf(var[d] + 1e-5f);
    float bias = beta[d] - mean[d] * inv;
    const float* xr = &x[((size_t)b * CD + d) * ND + n0 + tx * 4];
    float4 r;
    r.x = fmaxf(acc[i][0] * inv + bias, 0.f) + xr[0];
    r.y = fmaxf(acc[i][1] * inv + bias, 0.f) + xr[1];
    r.z = fmaxf(acc[i][2] * inv + bias, 0.f) + xr[2];
    r.w = fmaxf(acc[i][3] * inv + bias, 0.f) + xr[3];
    *(float4*)&out[((size_t)b * CD + d) * ND + n0 + tx * 4] = r;
  }
}

extern "C" void kernel_launch(void* const* d_in, const int* in_sizes, int n_in,
                              void* d_out, int out_size, void* d_ws, size_t ws_size,
                              hipStream_t stream) {
  const float* x     = (const float*)d_in[0];
  const float* Wq    = (const float*)d_in[1];
  const float* Wk    = (const float*)d_in[2];
  const float* Wv    = (const float*)d_in[3];
  const float* Wp    = (const float*)d_in[4];
  const float* gamma = (const float*)d_in[5];
  const float* beta  = (const float*)d_in[6];
  const float* mean  = (const float*)d_in[7];
  const float* var   = (const float*)d_in[8];
  float* out = (float*)d_out;

  float* ws  = (float*)d_ws;
  float* q   = ws;                            // B*N*DA   = 2,097,152
  float* kT  = q  + (size_t)BD * ND * DA;     // B*N*DA
  float* v   = kT + (size_t)BD * ND * DA;     // B*N*C    = 8,388,608
  float* Mc  = v  + (size_t)BD * ND * CD;     // B*N
  float* Dc  = Mc + (size_t)BD * ND;          // B*N
  float* fsa = Dc + (size_t)BD * ND;          // B*C*N    = 8,388,608

  dim3 blk(256);
  k_qkv<<<dim3(ND / 64, DA / 64, BD), blk, 0, stream>>>(x, Wq, q, DA);
  k_qkv<<<dim3(ND / 64, DA / 64, BD), blk, 0, stream>>>(x, Wk, kT, DA);
  k_qkv<<<dim3(ND / 64, CD / 64, BD), blk, 0, stream>>>(x, Wv, v, CD);
  k_colstats<<<dim3(ND / 64, BD), blk, 0, stream>>>(q, kT, Mc, Dc);
  k_attn<<<dim3(ND / 64, BD), blk, 0, stream>>>(q, kT, v, Mc, Dc, fsa);
  k_final<<<dim3(ND / 64, CD / 64, BD), blk, 0, stream>>>(x, fsa, Wp, gamma, beta,
                                                          mean, var, out);
}

// Round 2
// 1200.892 us; speedup vs baseline: 1.6996x; 1.6996x over previous
//
#include <hip/hip_runtime.h>
#include <math.h>

#define BD 8
#define CD 256
#define ND 4096
#define DA 64
#define CT 272  // C padded with ones-column block (row 256 = 1, 257..271 = 0)

typedef __attribute__((ext_vector_type(8))) short short8v;
typedef __attribute__((ext_vector_type(4))) float float4v;

static __device__ __forceinline__ float4v mfma16(short8v a, short8v b, float4v c) {
  return __builtin_amdgcn_mfma_f32_16x16x32_bf16(a, b, c, 0, 0, 0);
}

static __device__ __forceinline__ unsigned short f2bf(float f) {
  union { float f; unsigned int u; } v; v.f = f;
  unsigned int r = (v.u + 0x7fffu + ((v.u >> 16) & 1u)) >> 16;
  return (unsigned short)r;
}

// ---------------------------------------------------------------------------
// K1: fp32 projection for q/k, writing SPLIT bf16 (hi+lo) in [b][n][64] layout.
// grid (N/64, B), block 256. 64n x 64d tile, fp32 VALU (precision-critical).
// ---------------------------------------------------------------------------
__global__ __launch_bounds__(256) void k_projqk(const float* __restrict__ x,
                                                const float* __restrict__ W,
                                                unsigned short* __restrict__ ohi,
                                                unsigned short* __restrict__ olo) {
  const int n0 = blockIdx.x * 64;
  const int b  = blockIdx.y;
  __shared__ float Xs[16][68];
  __shared__ float Ws[16][68];
  const int tid = threadIdx.x;
  const int tx = tid & 15, ty = tid >> 4;
  float acc[4][4] = {};  // [i=n][j=d]
  const float* xb = x + (size_t)b * CD * ND + n0;
  for (int c0 = 0; c0 < CD; c0 += 16) {
    {
      int kk = tid >> 4, nn4 = (tid & 15) * 4;
      *(float4*)&Xs[kk][nn4] = *(const float4*)&xb[(size_t)(c0 + kk) * ND + nn4];
      int dd = tid >> 2, kc = (tid & 3) * 4;
      float4 w4 = *(const float4*)&W[(size_t)dd * CD + c0 + kc];
      Ws[kc + 0][dd] = w4.x; Ws[kc + 1][dd] = w4.y;
      Ws[kc + 2][dd] = w4.z; Ws[kc + 3][dd] = w4.w;
    }
    __syncthreads();
#pragma unroll
    for (int kk = 0; kk < 16; ++kk) {
      float4 a4 = *(const float4*)&Xs[kk][ty * 4];
      float4 b4 = *(const float4*)&Ws[kk][tx * 4];
      float a[4] = {a4.x, a4.y, a4.z, a4.w};
      float bb[4] = {b4.x, b4.y, b4.z, b4.w};
#pragma unroll
      for (int i = 0; i < 4; ++i)
#pragma unroll
        for (int j = 0; j < 4; ++j) acc[i][j] += a[i] * bb[j];
    }
    __syncthreads();
  }
#pragma unroll
  for (int i = 0; i < 4; ++i) {
    ushort4 h, l;
    float v0 = acc[i][0], v1 = acc[i][1], v2 = acc[i][2], v3 = acc[i][3];
    h.x = f2bf(v0); h.y = f2bf(v1); h.z = f2bf(v2); h.w = f2bf(v3);
    // lo = bf16(v - float(hi))
    union { unsigned int u; float f; } c0_, c1_, c2_, c3_;
    c0_.u = (unsigned int)h.x << 16; c1_.u = (unsigned int)h.y << 16;
    c2_.u = (unsigned int)h.z << 16; c3_.u = (unsigned int)h.w << 16;
    l.x = f2bf(v0 - c0_.f); l.y = f2bf(v1 - c1_.f);
    l.z = f2bf(v2 - c2_.f); l.w = f2bf(v3 - c3_.f);
    size_t o = ((size_t)b * ND + n0 + ty * 4 + i) * DA + tx * 4;
    *(ushort4*)&ohi[o] = h;
    *(ushort4*)&olo[o] = l;
  }
}

// ---------------------------------------------------------------------------
// K2: fp32 V projection, writing bf16 v^T in [b][c][m] layout (m contiguous).
// grid (N/64, C/64, B), block 256. acc[i=c][j=n], store along n.
// ---------------------------------------------------------------------------
__global__ __launch_bounds__(256) void k_projvT(const float* __restrict__ x,
                                                const float* __restrict__ Wv,
                                                unsigned short* __restrict__ vT) {
  const int n0 = blockIdx.x * 64;
  const int c0 = blockIdx.y * 64;
  const int b  = blockIdx.z;
  __shared__ float Xs[16][68];
  __shared__ float Ws[16][68];
  const int tid = threadIdx.x;
  const int tx = tid & 15, ty = tid >> 4;
  float acc[4][4] = {};  // [i=c][j=n]
  const float* xb = x + (size_t)b * CD * ND + n0;
  for (int k0 = 0; k0 < CD; k0 += 16) {
    {
      int kk = tid >> 4, nn4 = (tid & 15) * 4;
      *(float4*)&Xs[kk][nn4] = *(const float4*)&xb[(size_t)(k0 + kk) * ND + nn4];
      int dd = tid >> 2, kc = (tid & 3) * 4;
      float4 w4 = *(const float4*)&Wv[(size_t)(c0 + dd) * CD + k0 + kc];
      Ws[kc + 0][dd] = w4.x; Ws[kc + 1][dd] = w4.y;
      Ws[kc + 2][dd] = w4.z; Ws[kc + 3][dd] = w4.w;
    }
    __syncthreads();
#pragma unroll
    for (int kk = 0; kk < 16; ++kk) {
      float4 a4 = *(const float4*)&Ws[kk][ty * 4];  // c
      float4 b4 = *(const float4*)&Xs[kk][tx * 4];  // n
      float a[4] = {a4.x, a4.y, a4.z, a4.w};
      float bb[4] = {b4.x, b4.y, b4.z, b4.w};
#pragma unroll
      for (int i = 0; i < 4; ++i)
#pragma unroll
        for (int j = 0; j < 4; ++j) acc[i][j] += a[i] * bb[j];
    }
    __syncthreads();
  }
#pragma unroll
  for (int i = 0; i < 4; ++i) {
    ushort4 h;
    h.x = f2bf(acc[i][0]); h.y = f2bf(acc[i][1]);
    h.z = f2bf(acc[i][2]); h.w = f2bf(acc[i][3]);
    *(ushort4*)&vT[((size_t)b * CT + c0 + ty * 4 + i) * ND + n0 + tx * 4] = h;
  }
}

// fill vT padded rows 256..271 (row 256 = 1.0, rest 0). 512 blocks x 256.
__global__ void k_fill(unsigned short* __restrict__ vT) {
  int i = blockIdx.x * 256 + threadIdx.x;     // ushort4 index, 131072 total
  int b = i >> 14;                            // / (16*1024)
  int r = (i >> 10) & 15;                     // row within pad block
  int n4 = i & 1023;
  unsigned short val = (r == 0) ? (unsigned short)0x3F80 : (unsigned short)0;
  ushort4 v; v.x = val; v.y = val; v.z = val; v.w = val;
  *(ushort4*)&vT[((size_t)b * CT + 256 + r) * ND + n4 * 4] = v;
}

// cast Wp fp32 -> bf16. 64 blocks x 256.
__global__ void k_castWp(const float* __restrict__ Wp, unsigned short* __restrict__ Wpb) {
  int i = blockIdx.x * 256 + threadIdx.x;  // float4 index, 16384 total
  float4 f = *(const float4*)&Wp[(size_t)i * 4];
  ushort4 o; o.x = f2bf(f.x); o.y = f2bf(f.y); o.z = f2bf(f.z); o.w = f2bf(f.w);
  *(ushort4*)&Wpb[(size_t)i * 4] = o;
}

// ---------------------------------------------------------------------------
// K3: column-softmax denominators via MFMA.
// Drec[b][m] = 1 / sum_n exp(e[n][m]), e = qh*kh + qh*kl + ql*kh (split bf16).
// grid 512 (1D, b = bid&7 for XCD locality), block 256; wave w owns 16 m-cols.
// ---------------------------------------------------------------------------
__global__ __launch_bounds__(256) void k_colsum(const unsigned short* __restrict__ qh,
                                                const unsigned short* __restrict__ ql,
                                                const unsigned short* __restrict__ kh,
                                                const unsigned short* __restrict__ kl,
                                                float* __restrict__ Drec) {
  const int bid = blockIdx.x;
  const int b = bid & 7, m0 = (bid >> 3) * 64;
  const int tid = threadIdx.x;
  const int wave = tid >> 6, lane = tid & 63, lq = lane & 15, quad = lane >> 4;
  const int mw = m0 + wave * 16;
  const size_t kb = ((size_t)b * ND + mw + lq) * DA + quad * 8;
  short8v bkh0 = *(const short8v*)(kh + kb);
  short8v bkh1 = *(const short8v*)(kh + kb + 32);
  short8v bkl0 = *(const short8v*)(kl + kb);
  short8v bkl1 = *(const short8v*)(kl + kb + 32);
  float cs = 0.f;
  for (int n = 0; n < ND; n += 32) {
#pragma unroll
    for (int u = 0; u < 2; ++u) {
      const size_t qb = ((size_t)b * ND + n + u * 16 + lq) * DA + quad * 8;
      short8v a0 = *(const short8v*)(qh + qb);
      short8v a1 = *(const short8v*)(qh + qb + 32);
      short8v l0 = *(const short8v*)(ql + qb);
      short8v l1 = *(const short8v*)(ql + qb + 32);
      float4v acc = {0.f, 0.f, 0.f, 0.f};
      acc = mfma16(a0, bkh0, acc);
      acc = mfma16(a1, bkh1, acc);
      acc = mfma16(l0, bkh0, acc);
      acc = mfma16(l1, bkh1, acc);
      acc = mfma16(a0, bkl0, acc);
      acc = mfma16(a1, bkl1, acc);
      cs += __expf(acc[0]) + __expf(acc[1]) + __expf(acc[2]) + __expf(acc[3]);
    }
  }
  cs += __shfl_down(cs, 16, 64);
  cs += __shfl_down(cs, 32, 64);
  if (lane < 16) Drec[(size_t)b * ND + mw + lane] = 1.0f / cs;
}

// ---------------------------------------------------------------------------
// K4: main attention. Per block: 64 q-rows; wave w owns 16 rows, loops m-tiles
// of 64. e via split-bf16 MFMA -> P = exp(e)*Drec[m] -> per-wave LDS round
// trip (C-layout -> A-layout) -> O += P*V^T via MFMA. Ones-column of V gives
// row L1 sums S at c=256. Epilogue writes y = x - O/S as bf16 [b][n][c].
// No __syncthreads anywhere (P LDS is wave-private).
// ---------------------------------------------------------------------------
__global__ __launch_bounds__(256) void k_attn(const unsigned short* __restrict__ qh,
                                              const unsigned short* __restrict__ ql,
                                              const unsigned short* __restrict__ kh,
                                              const unsigned short* __restrict__ kl,
                                              const unsigned short* __restrict__ vT,
                                              const float* __restrict__ Drec,
                                              const float* __restrict__ x,
                                              unsigned short* __restrict__ y) {
  const int bid = blockIdx.x;
  const int b = bid & 7, n0 = (bid >> 3) * 64;
  const int tid = threadIdx.x;
  const int wave = tid >> 6, lane = tid & 63, lq = lane & 15, quad = lane >> 4;
  const int nw = n0 + wave * 16;
  __shared__ unsigned short Pw_all[4][16][72];  // per-wave P tile, padded rows
  unsigned short (*Pw)[72] = Pw_all[wave];

  const size_t qb = ((size_t)b * ND + nw + lq) * DA + quad * 8;
  short8v aqh0 = *(const short8v*)(qh + qb);
  short8v aqh1 = *(const short8v*)(qh + qb + 32);
  short8v aql0 = *(const short8v*)(ql + qb);
  short8v aql1 = *(const short8v*)(ql + qb + 32);

  float4v O[17];
#pragma unroll
  for (int t = 0; t < 17; ++t) O[t] = (float4v){0.f, 0.f, 0.f, 0.f};

  for (int m0 = 0; m0 < ND; m0 += 64) {
    float4v e[4];
#pragma unroll
    for (int s = 0; s < 4; ++s) {
      const size_t kb = ((size_t)b * ND + m0 + s * 16 + lq) * DA + quad * 8;
      short8v bkh0 = *(const short8v*)(kh + kb);
      short8v bkh1 = *(const short8v*)(kh + kb + 32);
      short8v bkl0 = *(const short8v*)(kl + kb);
      short8v bkl1 = *(const short8v*)(kl + kb + 32);
      float4v acc = {0.f, 0.f, 0.f, 0.f};
      acc = mfma16(aqh0, bkh0, acc);
      acc = mfma16(aqh1, bkh1, acc);
      acc = mfma16(aql0, bkh0, acc);
      acc = mfma16(aql1, bkh1, acc);
      acc = mfma16(aqh0, bkl0, acc);
      acc = mfma16(aqh1, bkl1, acc);
      e[s] = acc;
    }
    // P = exp(e) * Drec[m]; write bf16 into wave-private LDS tile [n][m]
#pragma unroll
    for (int s = 0; s < 4; ++s) {
      float dr = Drec[(size_t)b * ND + m0 + s * 16 + lq];
#pragma unroll
      for (int r = 0; r < 4; ++r) {
        float p = __expf(e[s][r]) * dr;
        Pw[quad * 4 + r][s * 16 + lq] = f2bf(p);
      }
    }
    // A-frags for PV from LDS (compiler inserts lgkmcnt; same-wave, no barrier)
    short8v ap0 = *(const short8v*)&Pw[lq][quad * 8];
    short8v ap1 = *(const short8v*)&Pw[lq][32 + quad * 8];
#pragma unroll
    for (int t = 0; t < 17; ++t) {
      const size_t vb = ((size_t)b * CT + t * 16 + lq) * ND + m0 + quad * 8;
      short8v bv0 = *(const short8v*)(vT + vb);
      short8v bv1 = *(const short8v*)(vT + vb + 32);
      O[t] = mfma16(ap0, bv0, O[t]);
      O[t] = mfma16(ap1, bv1, O[t]);
    }
  }
  // S[n] sits in O[16] col 0 (lanes with lq==0); broadcast within quad
  float rsc[4];
#pragma unroll
  for (int r = 0; r < 4; ++r) {
    float Sv = __shfl(O[16][r], quad * 16, 64);
    rsc[r] = 1.0f / (1e-9f + Sv);
  }
#pragma unroll
  for (int t = 0; t < 16; ++t) {
#pragma unroll
    for (int r = 0; r < 4; ++r) {
      int c = t * 16 + lq;
      int n = nw + quad * 4 + r;
      float xv = x[((size_t)b * CD + c) * ND + n];
      float yv = xv - O[t][r] * rsc[r];
      y[((size_t)b * ND + n) * CD + c] = f2bf(yv);
    }
  }
}

// ---------------------------------------------------------------------------
// K5: final conv + BN + relu + residual via MFMA.
// h[d][n] = sum_c Wp[d][c] * y[n][c]; out = relu(h*inv+bias) + x.
// grid 2048 (1D), block 256; wave w owns 16 d-rows x 64 n.
// ---------------------------------------------------------------------------
__global__ __launch_bounds__(256) void k_final(const unsigned short* __restrict__ y,
                                               const unsigned short* __restrict__ Wpb,
                                               const float* __restrict__ x,
                                               const float* __restrict__ gamma,
                                               const float* __restrict__ beta,
                                               const float* __restrict__ mean,
                                               const float* __restrict__ var,
                                               float* __restrict__ out) {
  const int bid = blockIdx.x;
  const int b = bid & 7;
  const int rem = bid >> 3;              // 0..255
  const int n0 = (rem & 63) * 64;
  const int d0 = (rem >> 6) * 64;
  const int tid = threadIdx.x;
  const int wave = tid >> 6, lane = tid & 63, lq = lane & 15, quad = lane >> 4;
  const int dw = d0 + wave * 16;
  float4v O[4];
#pragma unroll
  for (int s = 0; s < 4; ++s) O[s] = (float4v){0.f, 0.f, 0.f, 0.f};
#pragma unroll
  for (int ch = 0; ch < 8; ++ch) {
    const size_t ab = (size_t)(dw + lq) * CD + ch * 32 + quad * 8;
    short8v a0 = *(const short8v*)(Wpb + ab);
#pragma unroll
    for (int s = 0; s < 4; ++s) {
      const size_t bb = ((size_t)b * ND + n0 + s * 16 + lq) * CD + ch * 32 + quad * 8;
      short8v bv = *(const short8v*)(y + bb);
      O[s] = mfma16(a0, bv, O[s]);
    }
  }
#pragma unroll
  for (int r = 0; r < 4; ++r) {
    const int d = dw + quad * 4 + r;
    const float inv  = gamma[d] / sqrtf(var[d] + 1e-5f);
    const float bias = beta[d] - mean[d] * inv;
#pragma unroll
    for (int s = 0; s < 4; ++s) {
      const int n = n0 + s * 16 + lq;
      const size_t oi = ((size_t)b * CD + d) * ND + n;
      out[oi] = fmaxf(O[s][r] * inv + bias, 0.f) + x[oi];
    }
  }
}

extern "C" void kernel_launch(void* const* d_in, const int* in_sizes, int n_in,
                              void* d_out, int out_size, void* d_ws, size_t ws_size,
                              hipStream_t stream) {
  const float* x     = (const float*)d_in[0];
  const float* Wq    = (const float*)d_in[1];
  const float* Wk    = (const float*)d_in[2];
  const float* Wv    = (const float*)d_in[3];
  const float* Wp    = (const float*)d_in[4];
  const float* gamma = (const float*)d_in[5];
  const float* beta  = (const float*)d_in[6];
  const float* mean  = (const float*)d_in[7];
  const float* var   = (const float*)d_in[8];
  float* out = (float*)d_out;

  char* w = (char*)d_ws;
  unsigned short* qh = (unsigned short*)w; w += (size_t)BD * ND * DA * 2;
  unsigned short* ql = (unsigned short*)w; w += (size_t)BD * ND * DA * 2;
  unsigned short* kh = (unsigned short*)w; w += (size_t)BD * ND * DA * 2;
  unsigned short* kl = (unsigned short*)w; w += (size_t)BD * ND * DA * 2;
  unsigned short* vT = (unsigned short*)w; w += (size_t)BD * CT * ND * 2;
  unsigned short* yb = (unsigned short*)w; w += (size_t)BD * ND * CD * 2;
  unsigned short* Wpb = (unsigned short*)w; w += (size_t)CD * CD * 2;
  float* Drec = (float*)w; w += (size_t)BD * ND * 4;

  dim3 blk(256);
  k_projqk<<<dim3(ND / 64, BD), blk, 0, stream>>>(x, Wq, qh, ql);
  k_projqk<<<dim3(ND / 64, BD), blk, 0, stream>>>(x, Wk, kh, kl);
  k_projvT<<<dim3(ND / 64, CD / 64, BD), blk, 0, stream>>>(x, Wv, vT);
  k_fill<<<dim3(512), blk, 0, stream>>>(vT);
  k_castWp<<<dim3(64), blk, 0, stream>>>(Wp, Wpb);
  k_colsum<<<dim3(512), blk, 0, stream>>>(qh, ql, kh, kl, Drec);
  k_attn<<<dim3(512), blk, 0, stream>>>(qh, ql, kh, kl, vT, Drec, x, yb);
  k_final<<<dim3(2048), blk, 0, stream>>>(yb, Wpb, x, gamma, beta, mean, var, out);
}

// Round 3
// 831.393 us; speedup vs baseline: 2.4549x; 1.4444x over previous
//
#include <hip/hip_runtime.h>
#include <math.h>

#define BD 8
#define CD 256
#define ND 4096
#define DA 64
#define CT 272  // c-tiles staged: 0..255 data, 256 = ones row, 257..271 zero

typedef __attribute__((ext_vector_type(8))) short short8v;
typedef __attribute__((ext_vector_type(4))) float float4v;

static __device__ __forceinline__ float4v mfma16(short8v a, short8v b, float4v c) {
  return __builtin_amdgcn_mfma_f32_16x16x32_bf16(a, b, c, 0, 0, 0);
}
static __device__ __forceinline__ unsigned short f2bf(float f) {
  union { float f; unsigned int u; } v; v.f = f;
  return (unsigned short)((v.u + 0x7fffu + ((v.u >> 16) & 1u)) >> 16);
}
static __device__ __forceinline__ float bf2f(unsigned short h) {
  union { unsigned int u; float f; } v; v.u = (unsigned int)h << 16;
  return v.f;
}
// XOR-swizzled LDS offset (ushort units). Rows are 64 bf16 = 128 B = 8 chunks
// of 16 B. chunk' = chunk ^ (row&7) spreads frag reads across all 32 banks.
static __device__ __forceinline__ int sw(int row, int c8) {
  return row * 64 + (((c8) ^ (row & 7)) << 3);
}

// ---------------------------------------------------------------------------
// k_prep: x [b][c][n] fp32 -> xTh/xTl [b][n][256] split bf16 (transposed).
// ---------------------------------------------------------------------------
__global__ __launch_bounds__(256) void k_prep(const float* __restrict__ x,
                                              unsigned short* __restrict__ xTh,
                                              unsigned short* __restrict__ xTl) {
  const int n0 = blockIdx.x * 64, c0 = blockIdx.y * 64, b = blockIdx.z;
  __shared__ float Xs[64][68];
  const int tid = threadIdx.x;
  const int r0 = tid >> 4, col4 = (tid & 15) * 4;
#pragma unroll
  for (int j = 0; j < 4; ++j) {
    int r = r0 + j * 16;
    *(float4*)&Xs[r][col4] =
        *(const float4*)&x[((size_t)(b * CD + c0 + r)) * ND + n0 + col4];
  }
  __syncthreads();
  const int n = tid >> 2, cg = (tid & 3) * 16;
  unsigned short h[16], l[16];
#pragma unroll
  for (int j = 0; j < 16; ++j) {
    float v = Xs[cg + j][n];
    h[j] = f2bf(v);
    l[j] = f2bf(v - bf2f(h[j]));
  }
  size_t o = ((size_t)b * ND + n0 + n) * CD + c0 + cg;
#pragma unroll
  for (int j = 0; j < 4; ++j) {
    *(ushort4*)&xTh[o + j * 4] = *(ushort4*)&h[j * 4];
    *(ushort4*)&xTl[o + j * 4] = *(ushort4*)&l[j * 4];
  }
}

// ---------------------------------------------------------------------------
// k_prepW: split Wq/Wk/Wv/Wp fp32 -> bf16 hi/lo. grid 160 x 256.
// ---------------------------------------------------------------------------
__global__ void k_prepW(const float* __restrict__ Wq, const float* __restrict__ Wk,
                        const float* __restrict__ Wv, const float* __restrict__ Wp,
                        unsigned short* Wqh, unsigned short* Wql,
                        unsigned short* Wkh, unsigned short* Wkl,
                        unsigned short* Wvh, unsigned short* Wvl,
                        unsigned short* Wph, unsigned short* Wpl) {
  int i = blockIdx.x * 256 + threadIdx.x;  // 40960 float4s over 640 rows
  int row = i >> 6, c4 = (i & 63) * 4;
  const float* src; unsigned short *dh, *dl; int r;
  if (row < 64)       { src = Wq; dh = Wqh; dl = Wql; r = row; }
  else if (row < 128) { src = Wk; dh = Wkh; dl = Wkl; r = row - 64; }
  else if (row < 384) { src = Wv; dh = Wvh; dl = Wvl; r = row - 128; }
  else                { src = Wp; dh = Wph; dl = Wpl; r = row - 384; }
  float4 f = *(const float4*)&src[(size_t)r * 256 + c4];
  ushort4 hh, ll;
  hh.x = f2bf(f.x); hh.y = f2bf(f.y); hh.z = f2bf(f.z); hh.w = f2bf(f.w);
  ll.x = f2bf(f.x - bf2f(hh.x)); ll.y = f2bf(f.y - bf2f(hh.y));
  ll.z = f2bf(f.z - bf2f(hh.z)); ll.w = f2bf(f.w - bf2f(hh.w));
  *(ushort4*)&dh[(size_t)r * 256 + c4] = hh;
  *(ushort4*)&dl[(size_t)r * 256 + c4] = ll;
}

// ---------------------------------------------------------------------------
// k_proj64: out[n][64] (split hi/lo) = xT[n][c] . W[d][c], 3-product MFMA.
// grid (32 n-tiles of 128, B), block 256 (4 waves).
// ---------------------------------------------------------------------------
__global__ __launch_bounds__(256, 4) void k_proj64(
    const unsigned short* __restrict__ xTh, const unsigned short* __restrict__ xTl,
    const unsigned short* __restrict__ Wh, const unsigned short* __restrict__ Wl,
    unsigned short* __restrict__ oh, unsigned short* __restrict__ ol) {
  const int n0 = blockIdx.x * 128, b = blockIdx.y;
  const int tid = threadIdx.x, w = tid >> 6, lane = tid & 63, lq = lane & 15,
            quad = lane >> 4;
  const int nh = w & 1, dh = w >> 1;
  float4v O[2][4];
#pragma unroll
  for (int dt = 0; dt < 2; ++dt)
#pragma unroll
    for (int nt = 0; nt < 4; ++nt) O[dt][nt] = (float4v){0.f, 0.f, 0.f, 0.f};
#pragma unroll 2
  for (int ks = 0; ks < 8; ++ks) {
    short8v awh[2], awl[2], bxh[4], bxl[4];
#pragma unroll
    for (int dt = 0; dt < 2; ++dt) {
      size_t a = (size_t)(dh * 32 + dt * 16 + lq) * CD + ks * 32 + quad * 8;
      awh[dt] = *(const short8v*)(Wh + a);
      awl[dt] = *(const short8v*)(Wl + a);
    }
#pragma unroll
    for (int nt = 0; nt < 4; ++nt) {
      size_t a = ((size_t)b * ND + n0 + nh * 64 + nt * 16 + lq) * CD + ks * 32 + quad * 8;
      bxh[nt] = *(const short8v*)(xTh + a);
      bxl[nt] = *(const short8v*)(xTl + a);
    }
#pragma unroll
    for (int dt = 0; dt < 2; ++dt)
#pragma unroll
      for (int nt = 0; nt < 4; ++nt) {
        O[dt][nt] = mfma16(awh[dt], bxh[nt], O[dt][nt]);
        O[dt][nt] = mfma16(awl[dt], bxh[nt], O[dt][nt]);
        O[dt][nt] = mfma16(awh[dt], bxl[nt], O[dt][nt]);
      }
  }
#pragma unroll
  for (int dt = 0; dt < 2; ++dt)
#pragma unroll
    for (int nt = 0; nt < 4; ++nt) {
      int d0v = dh * 32 + dt * 16 + quad * 4;
      int n = n0 + nh * 64 + nt * 16 + lq;
      ushort4 hh, ll;
      float v0 = O[dt][nt][0], v1 = O[dt][nt][1], v2 = O[dt][nt][2], v3 = O[dt][nt][3];
      hh.x = f2bf(v0); hh.y = f2bf(v1); hh.z = f2bf(v2); hh.w = f2bf(v3);
      ll.x = f2bf(v0 - bf2f(hh.x)); ll.y = f2bf(v1 - bf2f(hh.y));
      ll.z = f2bf(v2 - bf2f(hh.z)); ll.w = f2bf(v3 - bf2f(hh.w));
      size_t o = ((size_t)b * ND + n) * DA + d0v;
      *(ushort4*)&oh[o] = hh;
      *(ushort4*)&ol[o] = ll;
    }
}

// ---------------------------------------------------------------------------
// k_projvT: vT[c_out][m] bf16 = xT[m][c] . Wv[c_out][c], 3-product MFMA.
// grid (32 m-tiles of 128, 4 c_out-tiles of 64, B), block 256.
// ---------------------------------------------------------------------------
__global__ __launch_bounds__(256, 4) void k_projvT(
    const unsigned short* __restrict__ xTh, const unsigned short* __restrict__ xTl,
    const unsigned short* __restrict__ Wvh, const unsigned short* __restrict__ Wvl,
    unsigned short* __restrict__ vT) {
  const int m0 = blockIdx.x * 128, cob = blockIdx.y * 64, b = blockIdx.z;
  const int tid = threadIdx.x, w = tid >> 6, lane = tid & 63, lq = lane & 15,
            quad = lane >> 4;
  const int mh = w & 1, ch2 = w >> 1;
  float4v O[2][4];
#pragma unroll
  for (int ct = 0; ct < 2; ++ct)
#pragma unroll
    for (int mt = 0; mt < 4; ++mt) O[ct][mt] = (float4v){0.f, 0.f, 0.f, 0.f};
#pragma unroll 2
  for (int ks = 0; ks < 8; ++ks) {
    short8v awh[2], awl[2], bxh[4], bxl[4];
#pragma unroll
    for (int ct = 0; ct < 2; ++ct) {
      size_t a = (size_t)(cob + ch2 * 32 + ct * 16 + lq) * CD + ks * 32 + quad * 8;
      awh[ct] = *(const short8v*)(Wvh + a);
      awl[ct] = *(const short8v*)(Wvl + a);
    }
#pragma unroll
    for (int mt = 0; mt < 4; ++mt) {
      size_t a = ((size_t)b * ND + m0 + mh * 64 + mt * 16 + lq) * CD + ks * 32 + quad * 8;
      bxh[mt] = *(const short8v*)(xTh + a);
      bxl[mt] = *(const short8v*)(xTl + a);
    }
#pragma unroll
    for (int ct = 0; ct < 2; ++ct)
#pragma unroll
      for (int mt = 0; mt < 4; ++mt) {
        O[ct][mt] = mfma16(awh[ct], bxh[mt], O[ct][mt]);
        O[ct][mt] = mfma16(awl[ct], bxh[mt], O[ct][mt]);
        O[ct][mt] = mfma16(awh[ct], bxl[mt], O[ct][mt]);
      }
  }
#pragma unroll
  for (int ct = 0; ct < 2; ++ct)
#pragma unroll
    for (int mt = 0; mt < 4; ++mt) {
      int m = m0 + mh * 64 + mt * 16 + lq;
#pragma unroll
      for (int r = 0; r < 4; ++r) {
        int co = cob + ch2 * 32 + ct * 16 + quad * 4 + r;
        vT[((size_t)b * CT + co) * ND + m] = f2bf(O[ct][mt][r]);
      }
    }
}

// fill vT rows 256..271 (row 256 = 1.0, rest 0). 512 blocks x 256.
__global__ void k_fill(unsigned short* __restrict__ vT) {
  int i = blockIdx.x * 256 + threadIdx.x;
  int b = i >> 14, r = (i >> 10) & 15, n4 = i & 1023;
  unsigned short val = (r == 0) ? (unsigned short)0x3F80 : (unsigned short)0;
  ushort4 v; v.x = val; v.y = val; v.z = val; v.w = val;
  *(ushort4*)&vT[((size_t)b * CT + 256 + r) * ND + n4 * 4] = v;
}

// ---------------------------------------------------------------------------
// k_colsum: Drec[b][m] = 1/sum_n exp(e[n][m]). Block 512 thr, owns 128 m.
// k-frags resident in registers; q staged (double-buffered, swizzled LDS).
// ---------------------------------------------------------------------------
__global__ __launch_bounds__(512, 2) void k_colsum(
    const unsigned short* __restrict__ qh, const unsigned short* __restrict__ ql,
    const unsigned short* __restrict__ kh, const unsigned short* __restrict__ kl,
    float* __restrict__ Drec) {
  const int bid = blockIdx.x, b = bid & 7, m0 = (bid >> 3) * 128;
  const int tid = threadIdx.x, w = tid >> 6, lane = tid & 63, lq = lane & 15,
            quad = lane >> 4;
  const int mq = w & 3, nh = w >> 2;
  __shared__ __align__(16) unsigned short qbuf[2][128 * 64];
  __shared__ float Cb[128];
  short8v bkh[2][2], bkl[2][2];
#pragma unroll
  for (int sub = 0; sub < 2; ++sub)
#pragma unroll
    for (int k = 0; k < 2; ++k) {
      size_t a = ((size_t)b * ND + m0 + mq * 32 + sub * 16 + lq) * DA + k * 32 + quad * 8;
      bkh[sub][k] = *(const short8v*)(kh + a);
      bkl[sub][k] = *(const short8v*)(kl + a);
    }
  uint4 sreg[2];
  const int srow = tid >> 3, sc8 = tid & 7;  // chunk for qh; +512 chunk is ql
  auto load_stage = [&](int nb) {
    sreg[0] = *(const uint4*)(qh + ((size_t)b * ND + nb + srow) * DA + sc8 * 8);
    sreg[1] = *(const uint4*)(ql + ((size_t)b * ND + nb + srow) * DA + sc8 * 8);
  };
  auto write_stage = [&](int buf) {
    *(uint4*)&qbuf[buf][sw(srow, sc8)] = sreg[0];
    *(uint4*)&qbuf[buf][sw(64 + srow, sc8)] = sreg[1];
  };
  load_stage(0); write_stage(0); load_stage(64);
  __syncthreads();
  float cs0 = 0.f, cs1 = 0.f;
  for (int i = 0; i < 64; ++i) {
    const int cur = i & 1;
#pragma unroll
    for (int s = 0; s < 2; ++s) {
      short8v ah[2], al[2];
#pragma unroll
      for (int k = 0; k < 2; ++k) {
        ah[k] = *(const short8v*)&qbuf[cur][sw(nh * 32 + s * 16 + lq, k * 4 + quad)];
        al[k] = *(const short8v*)&qbuf[cur][sw(64 + nh * 32 + s * 16 + lq, k * 4 + quad)];
      }
#pragma unroll
      for (int sub = 0; sub < 2; ++sub) {
        float4v acc = {0.f, 0.f, 0.f, 0.f};
#pragma unroll
        for (int k = 0; k < 2; ++k) {
          acc = mfma16(ah[k], bkh[sub][k], acc);
          acc = mfma16(al[k], bkh[sub][k], acc);
          acc = mfma16(ah[k], bkl[sub][k], acc);
        }
        float e0 = __expf(acc[0]) + __expf(acc[1]) + __expf(acc[2]) + __expf(acc[3]);
        if (sub == 0) cs0 += e0; else cs1 += e0;
      }
    }
    if (i < 63) { write_stage(1 - cur); if (i < 62) load_stage((i + 2) * 64); }
    __syncthreads();
  }
  cs0 += __shfl_down(cs0, 16); cs0 += __shfl_down(cs0, 32);
  cs1 += __shfl_down(cs1, 16); cs1 += __shfl_down(cs1, 32);
  if (nh == 0 && lane < 16) {
    Cb[mq * 32 + lane] = cs0;
    Cb[mq * 32 + 16 + lane] = cs1;
  }
  __syncthreads();
  if (nh == 1 && lane < 16) {
    float t0 = Cb[mq * 32 + lane] + cs0;
    float t1 = Cb[mq * 32 + 16 + lane] + cs1;
    Drec[(size_t)b * ND + m0 + mq * 32 + lane] = 1.0f / t0;
    Drec[(size_t)b * ND + m0 + mq * 32 + 16 + lane] = 1.0f / t1;
  }
}

// ---------------------------------------------------------------------------
// k_attn: flash-style main loop. Block 512 thr = 8 waves, BQ=128, BM=64.
// Wave (nq, ch): e-phase computes e[32n x 32m] (ms=ch), PV accumulates
// O[32n x 144c] (c-tiles ch*9..). k/vT double-buffered in swizzled LDS,
// P round-trips through LDS, ones-column of vT yields row sums S.
// ---------------------------------------------------------------------------
__global__ __launch_bounds__(512, 2) void k_attn(
    const unsigned short* __restrict__ qh, const unsigned short* __restrict__ ql,
    const unsigned short* __restrict__ kh, const unsigned short* __restrict__ kl,
    const unsigned short* __restrict__ vT, const float* __restrict__ Drec,
    const float* __restrict__ x, unsigned short* __restrict__ y) {
  const int bid = blockIdx.x, b = bid & 7, n0 = (bid >> 3) * 128;
  const int tid = threadIdx.x, w = tid >> 6, lane = tid & 63, lq = lane & 15,
            quad = lane >> 4;
  const int nq = w & 3, ch = w >> 2;
  __shared__ __align__(16) unsigned short kbuf[2][128 * 64];
  __shared__ __align__(16) unsigned short vbuf[2][CT * 64];
  __shared__ __align__(16) unsigned short Pb[128 * 64];
  __shared__ float DrecS[ND];
  __shared__ float Sb[128];
  for (int i = tid; i < ND / 4; i += 512)
    *(float4*)&DrecS[i * 4] = *(const float4*)&Drec[(size_t)b * ND + i * 4];
  short8v aq[2][2][2];
#pragma unroll
  for (int s = 0; s < 2; ++s)
#pragma unroll
    for (int k = 0; k < 2; ++k) {
      size_t a = ((size_t)b * ND + n0 + nq * 32 + s * 16 + lq) * DA + k * 32 + quad * 8;
      aq[s][k][0] = *(const short8v*)(qh + a);
      aq[s][k][1] = *(const short8v*)(ql + a);
    }
  float4v O[2][9];
#pragma unroll
  for (int s = 0; s < 2; ++s)
#pragma unroll
    for (int t = 0; t < 9; ++t) O[s][t] = (float4v){0.f, 0.f, 0.f, 0.f};

  uint4 sk0, sk1, sv[5];
  const int srow = tid >> 3, sc8 = tid & 7;
  auto load_stage = [&](int mb) {
    sk0 = *(const uint4*)(kh + ((size_t)b * ND + mb + srow) * DA + sc8 * 8);
    sk1 = *(const uint4*)(kl + ((size_t)b * ND + mb + srow) * DA + sc8 * 8);
#pragma unroll
    for (int j = 0; j < 4; ++j) {
      int c = tid + j * 512;
      sv[j] = *(const uint4*)(vT + ((size_t)b * CT + (c >> 3)) * ND + mb + (c & 7) * 8);
    }
    if (tid < 128) {
      int c = 2048 + tid;
      sv[4] = *(const uint4*)(vT + ((size_t)b * CT + (c >> 3)) * ND + mb + (c & 7) * 8);
    }
  };
  auto write_stage = [&](int buf) {
    *(uint4*)&kbuf[buf][sw(srow, sc8)] = sk0;
    *(uint4*)&kbuf[buf][sw(64 + srow, sc8)] = sk1;
#pragma unroll
    for (int j = 0; j < 4; ++j) {
      int c = tid + j * 512;
      *(uint4*)&vbuf[buf][sw(c >> 3, c & 7)] = sv[j];
    }
    if (tid < 128) {
      int c = 2048 + tid;
      *(uint4*)&vbuf[buf][sw(c >> 3, c & 7)] = sv[4];
    }
  };
  load_stage(0); write_stage(0); load_stage(64);
  __syncthreads();

#pragma unroll 1
  for (int i = 0; i < 64; ++i) {
    const int cur = i & 1, m0 = i * 64;
    // ---- e-phase: e[nq-strip][ch m-half] -> P (bf16 in LDS) ----
#pragma unroll
    for (int sub = 0; sub < 2; ++sub) {
      short8v bh[2], bl[2];
#pragma unroll
      for (int k = 0; k < 2; ++k) {
        bh[k] = *(const short8v*)&kbuf[cur][sw(ch * 32 + sub * 16 + lq, k * 4 + quad)];
        bl[k] = *(const short8v*)&kbuf[cur][sw(64 + ch * 32 + sub * 16 + lq, k * 4 + quad)];
      }
      const int m_loc = ch * 32 + sub * 16 + lq;
      const float dr = DrecS[m0 + m_loc];
#pragma unroll
      for (int s = 0; s < 2; ++s) {
        float4v acc = {0.f, 0.f, 0.f, 0.f};
#pragma unroll
        for (int k = 0; k < 2; ++k) {
          acc = mfma16(aq[s][k][0], bh[k], acc);
          acc = mfma16(aq[s][k][1], bh[k], acc);
          acc = mfma16(aq[s][k][0], bl[k], acc);
        }
        const int nrow = nq * 32 + s * 16 + quad * 4;
#pragma unroll
        for (int r = 0; r < 4; ++r) {
          float p = __expf(acc[r]) * dr;
          const int n_loc = nrow + r;
          Pb[n_loc * 64 + ((((m_loc >> 3) ^ (n_loc & 7)) << 3) | (m_loc & 7))] = f2bf(p);
        }
      }
    }
    if (i < 63) { write_stage(1 - cur); if (i < 62) load_stage((i + 2) * 64); }
    __syncthreads();
    // ---- PV-phase ----
    short8v ap[2][2];
#pragma unroll
    for (int s = 0; s < 2; ++s)
#pragma unroll
      for (int k = 0; k < 2; ++k)
        ap[s][k] = *(const short8v*)&Pb[sw(nq * 32 + s * 16 + lq, k * 4 + quad)];
    const int tbase = ch * 9;
#pragma unroll
    for (int ti = 0; ti < 8; ++ti) {
      const int t = tbase + ti;
#pragma unroll
      for (int k = 0; k < 2; ++k) {
        short8v bv = *(const short8v*)&vbuf[cur][sw(t * 16 + lq, k * 4 + quad)];
#pragma unroll
        for (int s = 0; s < 2; ++s) O[s][ti] = mfma16(ap[s][k], bv, O[s][ti]);
      }
    }
    if (ch == 0) {  // 9th tile (t=8) for ch0 only
#pragma unroll
      for (int k = 0; k < 2; ++k) {
        short8v bv = *(const short8v*)&vbuf[cur][sw(8 * 16 + lq, k * 4 + quad)];
#pragma unroll
        for (int s = 0; s < 2; ++s) O[s][8] = mfma16(ap[s][k], bv, O[s][8]);
      }
    }
    __syncthreads();
  }
  // ---- epilogue: S from ones-column (t=16, ti=7 of ch1), y = x - O/S ----
  if (ch == 1 && lq == 0) {
#pragma unroll
    for (int s = 0; s < 2; ++s)
#pragma unroll
      for (int r = 0; r < 4; ++r)
        Sb[nq * 32 + s * 16 + quad * 4 + r] = O[s][7][r];
  }
  __syncthreads();
  float rsc[2][4];
#pragma unroll
  for (int s = 0; s < 2; ++s)
#pragma unroll
    for (int r = 0; r < 4; ++r)
      rsc[s][r] = 1.0f / (1e-9f + Sb[nq * 32 + s * 16 + quad * 4 + r]);
  const int tcnt2 = ch ? 7 : 9;
  for (int ti = 0; ti < tcnt2; ++ti) {
    const int c = (ch * 9 + ti) * 16 + lq;
#pragma unroll
    for (int s = 0; s < 2; ++s)
#pragma unroll
      for (int r = 0; r < 4; ++r) {
        const int n = n0 + nq * 32 + s * 16 + quad * 4 + r;
        float xv = x[((size_t)(b * CD + c)) * ND + n];
        y[((size_t)b * ND + n) * CD + c] = f2bf(xv - O[s][ti][r] * rsc[s][r]);
      }
  }
}

// ---------------------------------------------------------------------------
// k_final: h = Wp . y (bf16 MFMA); out = relu(BN(h)) + x. (unchanged from R2)
// ---------------------------------------------------------------------------
__global__ __launch_bounds__(256) void k_final(const unsigned short* __restrict__ y,
                                               const unsigned short* __restrict__ Wpb,
                                               const float* __restrict__ x,
                                               const float* __restrict__ gamma,
                                               const float* __restrict__ beta,
                                               const float* __restrict__ mean,
                                               const float* __restrict__ var,
                                               float* __restrict__ out) {
  const int bid = blockIdx.x;
  const int b = bid & 7;
  const int rem = bid >> 3;
  const int n0 = (rem & 63) * 64;
  const int d0 = (rem >> 6) * 64;
  const int tid = threadIdx.x;
  const int wave = tid >> 6, lane = tid & 63, lq = lane & 15, quad = lane >> 4;
  const int dw = d0 + wave * 16;
  float4v O[4];
#pragma unroll
  for (int s = 0; s < 4; ++s) O[s] = (float4v){0.f, 0.f, 0.f, 0.f};
#pragma unroll
  for (int chh = 0; chh < 8; ++chh) {
    const size_t ab = (size_t)(dw + lq) * CD + chh * 32 + quad * 8;
    short8v a0 = *(const short8v*)(Wpb + ab);
#pragma unroll
    for (int s = 0; s < 4; ++s) {
      const size_t bb = ((size_t)b * ND + n0 + s * 16 + lq) * CD + chh * 32 + quad * 8;
      short8v bv = *(const short8v*)(y + bb);
      O[s] = mfma16(a0, bv, O[s]);
    }
  }
#pragma unroll
  for (int r = 0; r < 4; ++r) {
    const int d = dw + quad * 4 + r;
    const float inv  = gamma[d] / sqrtf(var[d] + 1e-5f);
    const float bias = beta[d] - mean[d] * inv;
#pragma unroll
    for (int s = 0; s < 4; ++s) {
      const int n = n0 + s * 16 + lq;
      const size_t oi = ((size_t)b * CD + d) * ND + n;
      out[oi] = fmaxf(O[s][r] * inv + bias, 0.f) + x[oi];
    }
  }
}

extern "C" void kernel_launch(void* const* d_in, const int* in_sizes, int n_in,
                              void* d_out, int out_size, void* d_ws, size_t ws_size,
                              hipStream_t stream) {
  const float* x     = (const float*)d_in[0];
  const float* Wq    = (const float*)d_in[1];
  const float* Wk    = (const float*)d_in[2];
  const float* Wv    = (const float*)d_in[3];
  const float* Wp    = (const float*)d_in[4];
  const float* gamma = (const float*)d_in[5];
  const float* beta  = (const float*)d_in[6];
  const float* mean  = (const float*)d_in[7];
  const float* var   = (const float*)d_in[8];
  float* out = (float*)d_out;

  char* wsp = (char*)d_ws;
  unsigned short* qh  = (unsigned short*)wsp; wsp += (size_t)BD * ND * DA * 2;
  unsigned short* ql  = (unsigned short*)wsp; wsp += (size_t)BD * ND * DA * 2;
  unsigned short* khp = (unsigned short*)wsp; wsp += (size_t)BD * ND * DA * 2;
  unsigned short* klp = (unsigned short*)wsp; wsp += (size_t)BD * ND * DA * 2;
  unsigned short* vT  = (unsigned short*)wsp; wsp += (size_t)BD * CT * ND * 2;
  unsigned short* xTh = (unsigned short*)wsp; wsp += (size_t)BD * ND * CD * 2;  // aliased as y
  unsigned short* xTl = (unsigned short*)wsp; wsp += (size_t)BD * ND * CD * 2;
  unsigned short* Wqh = (unsigned short*)wsp; wsp += (size_t)64 * 256 * 2;
  unsigned short* Wql = (unsigned short*)wsp; wsp += (size_t)64 * 256 * 2;
  unsigned short* Wkh = (unsigned short*)wsp; wsp += (size_t)64 * 256 * 2;
  unsigned short* Wkl = (unsigned short*)wsp; wsp += (size_t)64 * 256 * 2;
  unsigned short* Wvh = (unsigned short*)wsp; wsp += (size_t)256 * 256 * 2;
  unsigned short* Wvl = (unsigned short*)wsp; wsp += (size_t)256 * 256 * 2;
  unsigned short* Wph = (unsigned short*)wsp; wsp += (size_t)256 * 256 * 2;
  unsigned short* Wpl = (unsigned short*)wsp; wsp += (size_t)256 * 256 * 2;
  float* Drec = (float*)wsp; wsp += (size_t)BD * ND * 4;
  unsigned short* y = xTh;  // alias: xTh dead after projections

  dim3 blk(256), blk5(512);
  k_prep<<<dim3(ND / 64, CD / 64, BD), blk, 0, stream>>>(x, xTh, xTl);
  k_prepW<<<dim3(160), blk, 0, stream>>>(Wq, Wk, Wv, Wp, Wqh, Wql, Wkh, Wkl,
                                         Wvh, Wvl, Wph, Wpl);
  k_proj64<<<dim3(ND / 128, BD), blk, 0, stream>>>(xTh, xTl, Wqh, Wql, qh, ql);
  k_proj64<<<dim3(ND / 128, BD), blk, 0, stream>>>(xTh, xTl, Wkh, Wkl, khp, klp);
  k_projvT<<<dim3(ND / 128, 4, BD), blk, 0, stream>>>(xTh, xTl, Wvh, Wvl, vT);
  k_fill<<<dim3(512), blk, 0, stream>>>(vT);
  k_colsum<<<dim3(256), blk5, 0, stream>>>(qh, ql, khp, klp, Drec);
  k_attn<<<dim3(256), blk5, 0, stream>>>(qh, ql, khp, klp, vT, Drec, x, y);
  k_final<<<dim3(2048), blk, 0, stream>>>(y, Wph, x, gamma, beta, mean, var, out);
}

// Round 4
// 532.638 us; speedup vs baseline: 3.8319x; 1.5609x over previous
//
#include <hip/hip_runtime.h>
#include <math.h>

#define BD 8
#define CD 256
#define ND 4096
#define DA 64
#define CT 272  // c-tiles staged: 0..255 data, 256 = ones row, 257..271 zero

typedef __attribute__((ext_vector_type(8))) short short8v;
typedef __attribute__((ext_vector_type(4))) float float4v;

static __device__ __forceinline__ float4v mfma16(short8v a, short8v b, float4v c) {
  return __builtin_amdgcn_mfma_f32_16x16x32_bf16(a, b, c, 0, 0, 0);
}
static __device__ __forceinline__ unsigned short f2bf(float f) {
  union { float f; unsigned int u; } v; v.f = f;
  return (unsigned short)((v.u + 0x7fffu + ((v.u >> 16) & 1u)) >> 16);
}
static __device__ __forceinline__ float bf2f(unsigned short h) {
  union { unsigned int u; float f; } v; v.u = (unsigned int)h << 16;
  return v.f;
}
// XOR-swizzled LDS offset (ushort units). Rows are 64 bf16 = 128 B = 8 chunks
// of 16 B. chunk' = chunk ^ (row&7) spreads frag reads across all 32 banks.
static __device__ __forceinline__ int sw(int row, int c8) {
  return row * 64 + (((c8) ^ (row & 7)) << 3);
}

// ---------------------------------------------------------------------------
// k_prep: x [b][c][n] fp32 -> xTh/xTl [b][n][256] split bf16 (transposed).
// ---------------------------------------------------------------------------
__global__ __launch_bounds__(256) void k_prep(const float* __restrict__ x,
                                              unsigned short* __restrict__ xTh,
                                              unsigned short* __restrict__ xTl) {
  const int n0 = blockIdx.x * 64, c0 = blockIdx.y * 64, b = blockIdx.z;
  __shared__ float Xs[64][68];
  const int tid = threadIdx.x;
  const int r0 = tid >> 4, col4 = (tid & 15) * 4;
#pragma unroll
  for (int j = 0; j < 4; ++j) {
    int r = r0 + j * 16;
    *(float4*)&Xs[r][col4] =
        *(const float4*)&x[((size_t)(b * CD + c0 + r)) * ND + n0 + col4];
  }
  __syncthreads();
  const int n = tid >> 2, cg = (tid & 3) * 16;
  unsigned short h[16], l[16];
#pragma unroll
  for (int j = 0; j < 16; ++j) {
    float v = Xs[cg + j][n];
    h[j] = f2bf(v);
    l[j] = f2bf(v - bf2f(h[j]));
  }
  size_t o = ((size_t)b * ND + n0 + n) * CD + c0 + cg;
#pragma unroll
  for (int j = 0; j < 4; ++j) {
    *(ushort4*)&xTh[o + j * 4] = *(ushort4*)&h[j * 4];
    *(ushort4*)&xTl[o + j * 4] = *(ushort4*)&l[j * 4];
  }
}

// ---------------------------------------------------------------------------
// k_prepW: split Wq/Wk/Wv/Wp fp32 -> bf16 hi/lo. grid 160 x 256.
// ---------------------------------------------------------------------------
__global__ void k_prepW(const float* __restrict__ Wq, const float* __restrict__ Wk,
                        const float* __restrict__ Wv, const float* __restrict__ Wp,
                        unsigned short* Wqh, unsigned short* Wql,
                        unsigned short* Wkh, unsigned short* Wkl,
                        unsigned short* Wvh, unsigned short* Wvl,
                        unsigned short* Wph, unsigned short* Wpl) {
  int i = blockIdx.x * 256 + threadIdx.x;  // 40960 float4s over 640 rows
  int row = i >> 6, c4 = (i & 63) * 4;
  const float* src; unsigned short *dh, *dl; int r;
  if (row < 64)       { src = Wq; dh = Wqh; dl = Wql; r = row; }
  else if (row < 128) { src = Wk; dh = Wkh; dl = Wkl; r = row - 64; }
  else if (row < 384) { src = Wv; dh = Wvh; dl = Wvl; r = row - 128; }
  else                { src = Wp; dh = Wph; dl = Wpl; r = row - 384; }
  float4 f = *(const float4*)&src[(size_t)r * 256 + c4];
  ushort4 hh, ll;
  hh.x = f2bf(f.x); hh.y = f2bf(f.y); hh.z = f2bf(f.z); hh.w = f2bf(f.w);
  ll.x = f2bf(f.x - bf2f(hh.x)); ll.y = f2bf(f.y - bf2f(hh.y));
  ll.z = f2bf(f.z - bf2f(hh.z)); ll.w = f2bf(f.w - bf2f(hh.w));
  *(ushort4*)&dh[(size_t)r * 256 + c4] = hh;
  *(ushort4*)&dl[(size_t)r * 256 + c4] = ll;
}

// ---------------------------------------------------------------------------
// k_proj64: out[n][64] (split hi/lo) = xT[n][c] . W[d][c], 3-product MFMA.
// grid (32 n-tiles of 128, B), block 256 (4 waves).
// ---------------------------------------------------------------------------
__global__ __launch_bounds__(256, 4) void k_proj64(
    const unsigned short* __restrict__ xTh, const unsigned short* __restrict__ xTl,
    const unsigned short* __restrict__ Wh, const unsigned short* __restrict__ Wl,
    unsigned short* __restrict__ oh, unsigned short* __restrict__ ol) {
  const int n0 = blockIdx.x * 128, b = blockIdx.y;
  const int tid = threadIdx.x, w = tid >> 6, lane = tid & 63, lq = lane & 15,
            quad = lane >> 4;
  const int nh = w & 1, dh = w >> 1;
  float4v O[2][4];
#pragma unroll
  for (int dt = 0; dt < 2; ++dt)
#pragma unroll
    for (int nt = 0; nt < 4; ++nt) O[dt][nt] = (float4v){0.f, 0.f, 0.f, 0.f};
#pragma unroll 2
  for (int ks = 0; ks < 8; ++ks) {
    short8v awh[2], awl[2], bxh[4], bxl[4];
#pragma unroll
    for (int dt = 0; dt < 2; ++dt) {
      size_t a = (size_t)(dh * 32 + dt * 16 + lq) * CD + ks * 32 + quad * 8;
      awh[dt] = *(const short8v*)(Wh + a);
      awl[dt] = *(const short8v*)(Wl + a);
    }
#pragma unroll
    for (int nt = 0; nt < 4; ++nt) {
      size_t a = ((size_t)b * ND + n0 + nh * 64 + nt * 16 + lq) * CD + ks * 32 + quad * 8;
      bxh[nt] = *(const short8v*)(xTh + a);
      bxl[nt] = *(const short8v*)(xTl + a);
    }
#pragma unroll
    for (int dt = 0; dt < 2; ++dt)
#pragma unroll
      for (int nt = 0; nt < 4; ++nt) {
        O[dt][nt] = mfma16(awh[dt], bxh[nt], O[dt][nt]);
        O[dt][nt] = mfma16(awl[dt], bxh[nt], O[dt][nt]);
        O[dt][nt] = mfma16(awh[dt], bxl[nt], O[dt][nt]);
      }
  }
#pragma unroll
  for (int dt = 0; dt < 2; ++dt)
#pragma unroll
    for (int nt = 0; nt < 4; ++nt) {
      int d0v = dh * 32 + dt * 16 + quad * 4;
      int n = n0 + nh * 64 + nt * 16 + lq;
      ushort4 hh, ll;
      float v0 = O[dt][nt][0], v1 = O[dt][nt][1], v2 = O[dt][nt][2], v3 = O[dt][nt][3];
      hh.x = f2bf(v0); hh.y = f2bf(v1); hh.z = f2bf(v2); hh.w = f2bf(v3);
      ll.x = f2bf(v0 - bf2f(hh.x)); ll.y = f2bf(v1 - bf2f(hh.y));
      ll.z = f2bf(v2 - bf2f(hh.z)); ll.w = f2bf(v3 - bf2f(hh.w));
      size_t o = ((size_t)b * ND + n) * DA + d0v;
      *(ushort4*)&oh[o] = hh;
      *(ushort4*)&ol[o] = ll;
    }
}

// ---------------------------------------------------------------------------
// k_projvT: vT[c_out][m] bf16 = xT[m][c] . Wv[c_out][c], 3-product MFMA.
// grid (32 m-tiles of 128, 4 c_out-tiles of 64, B), block 256.
// ---------------------------------------------------------------------------
__global__ __launch_bounds__(256, 4) void k_projvT(
    const unsigned short* __restrict__ xTh, const unsigned short* __restrict__ xTl,
    const unsigned short* __restrict__ Wvh, const unsigned short* __restrict__ Wvl,
    unsigned short* __restrict__ vT) {
  const int m0 = blockIdx.x * 128, cob = blockIdx.y * 64, b = blockIdx.z;
  const int tid = threadIdx.x, w = tid >> 6, lane = tid & 63, lq = lane & 15,
            quad = lane >> 4;
  const int mh = w & 1, ch2 = w >> 1;
  float4v O[2][4];
#pragma unroll
  for (int ct = 0; ct < 2; ++ct)
#pragma unroll
    for (int mt = 0; mt < 4; ++mt) O[ct][mt] = (float4v){0.f, 0.f, 0.f, 0.f};
#pragma unroll 2
  for (int ks = 0; ks < 8; ++ks) {
    short8v awh[2], awl[2], bxh[4], bxl[4];
#pragma unroll
    for (int ct = 0; ct < 2; ++ct) {
      size_t a = (size_t)(cob + ch2 * 32 + ct * 16 + lq) * CD + ks * 32 + quad * 8;
      awh[ct] = *(const short8v*)(Wvh + a);
      awl[ct] = *(const short8v*)(Wvl + a);
    }
#pragma unroll
    for (int mt = 0; mt < 4; ++mt) {
      size_t a = ((size_t)b * ND + m0 + mh * 64 + mt * 16 + lq) * CD + ks * 32 + quad * 8;
      bxh[mt] = *(const short8v*)(xTh + a);
      bxl[mt] = *(const short8v*)(xTl + a);
    }
#pragma unroll
    for (int ct = 0; ct < 2; ++ct)
#pragma unroll
      for (int mt = 0; mt < 4; ++mt) {
        O[ct][mt] = mfma16(awh[ct], bxh[mt], O[ct][mt]);
        O[ct][mt] = mfma16(awl[ct], bxh[mt], O[ct][mt]);
        O[ct][mt] = mfma16(awh[ct], bxl[mt], O[ct][mt]);
      }
  }
#pragma unroll
  for (int ct = 0; ct < 2; ++ct)
#pragma unroll
    for (int mt = 0; mt < 4; ++mt) {
      int m = m0 + mh * 64 + mt * 16 + lq;
#pragma unroll
      for (int r = 0; r < 4; ++r) {
        int co = cob + ch2 * 32 + ct * 16 + quad * 4 + r;
        vT[((size_t)b * CT + co) * ND + m] = f2bf(O[ct][mt][r]);
      }
    }
}

// fill vT rows 256..271 (row 256 = 1.0, rest 0). 512 blocks x 256.
__global__ void k_fill(unsigned short* __restrict__ vT) {
  int i = blockIdx.x * 256 + threadIdx.x;
  int b = i >> 14, r = (i >> 10) & 15, n4 = i & 1023;
  unsigned short val = (r == 0) ? (unsigned short)0x3F80 : (unsigned short)0;
  ushort4 v; v.x = val; v.y = val; v.z = val; v.w = val;
  *(ushort4*)&vT[((size_t)b * CT + 256 + r) * ND + n4 * 4] = v;
}

// ---------------------------------------------------------------------------
// k_colsum: Drec[b][m] = 1/sum_n exp(e[n][m]). Block 512 thr, owns 128 m.
// k-frags resident in registers; q staged (double-buffered, swizzled LDS).
// ---------------------------------------------------------------------------
__global__ __launch_bounds__(512, 2) void k_colsum(
    const unsigned short* __restrict__ qh, const unsigned short* __restrict__ ql,
    const unsigned short* __restrict__ kh, const unsigned short* __restrict__ kl,
    float* __restrict__ Drec) {
  const int bid = blockIdx.x, b = bid & 7, m0 = (bid >> 3) * 128;
  const int tid = threadIdx.x, w = tid >> 6, lane = tid & 63, lq = lane & 15,
            quad = lane >> 4;
  const int mq = w & 3, nh = w >> 2;
  __shared__ __align__(16) unsigned short qbuf[2][128 * 64];
  __shared__ float Cb[128];
  short8v bkh[2][2], bkl[2][2];
#pragma unroll
  for (int sub = 0; sub < 2; ++sub)
#pragma unroll
    for (int k = 0; k < 2; ++k) {
      size_t a = ((size_t)b * ND + m0 + mq * 32 + sub * 16 + lq) * DA + k * 32 + quad * 8;
      bkh[sub][k] = *(const short8v*)(kh + a);
      bkl[sub][k] = *(const short8v*)(kl + a);
    }
  uint4 sreg[2];
  const int srow = tid >> 3, sc8 = tid & 7;  // chunk for qh; +512 chunk is ql
  auto load_stage = [&](int nb) {
    sreg[0] = *(const uint4*)(qh + ((size_t)b * ND + nb + srow) * DA + sc8 * 8);
    sreg[1] = *(const uint4*)(ql + ((size_t)b * ND + nb + srow) * DA + sc8 * 8);
  };
  auto write_stage = [&](int buf) {
    *(uint4*)&qbuf[buf][sw(srow, sc8)] = sreg[0];
    *(uint4*)&qbuf[buf][sw(64 + srow, sc8)] = sreg[1];
  };
  load_stage(0); write_stage(0); load_stage(64);
  __syncthreads();
  float cs0 = 0.f, cs1 = 0.f;
  for (int i = 0; i < 64; ++i) {
    const int cur = i & 1;
#pragma unroll
    for (int s = 0; s < 2; ++s) {
      short8v ah[2], al[2];
#pragma unroll
      for (int k = 0; k < 2; ++k) {
        ah[k] = *(const short8v*)&qbuf[cur][sw(nh * 32 + s * 16 + lq, k * 4 + quad)];
        al[k] = *(const short8v*)&qbuf[cur][sw(64 + nh * 32 + s * 16 + lq, k * 4 + quad)];
      }
#pragma unroll
      for (int sub = 0; sub < 2; ++sub) {
        float4v acc = {0.f, 0.f, 0.f, 0.f};
#pragma unroll
        for (int k = 0; k < 2; ++k) {
          acc = mfma16(ah[k], bkh[sub][k], acc);
          acc = mfma16(al[k], bkh[sub][k], acc);
          acc = mfma16(ah[k], bkl[sub][k], acc);
        }
        float e0 = __expf(acc[0]) + __expf(acc[1]) + __expf(acc[2]) + __expf(acc[3]);
        if (sub == 0) cs0 += e0; else cs1 += e0;
      }
    }
    if (i < 63) { write_stage(1 - cur); if (i < 62) load_stage((i + 2) * 64); }
    __syncthreads();
  }
  cs0 += __shfl_down(cs0, 16); cs0 += __shfl_down(cs0, 32);
  cs1 += __shfl_down(cs1, 16); cs1 += __shfl_down(cs1, 32);
  if (nh == 0 && lane < 16) {
    Cb[mq * 32 + lane] = cs0;
    Cb[mq * 32 + 16 + lane] = cs1;
  }
  __syncthreads();
  if (nh == 1 && lane < 16) {
    float t0 = Cb[mq * 32 + lane] + cs0;
    float t1 = Cb[mq * 32 + 16 + lane] + cs1;
    Drec[(size_t)b * ND + m0 + mq * 32 + lane] = 1.0f / t0;
    Drec[(size_t)b * ND + m0 + mq * 32 + 16 + lane] = 1.0f / t1;
  }
}

// ---------------------------------------------------------------------------
// k_attn: flash-style main loop. Block 512 thr = 8 waves, BQ=128, BM=64.
// Wave (nq, ch): e-phase computes e[32n x 32m] (ms=ch), PV accumulates
// O[32n x 144c] (c-tiles ch*9..). k/vT double-buffered in swizzled LDS,
// P round-trips through LDS, ones-column of vT yields row sums S.
// NOTE: epilogue loops MUST be compile-time unrolled with constant O indices;
// a runtime trip count demotes O[][] to scratch (R3: 2.9 GB HBM writes).
// ---------------------------------------------------------------------------
__global__ __launch_bounds__(512, 2) void k_attn(
    const unsigned short* __restrict__ qh, const unsigned short* __restrict__ ql,
    const unsigned short* __restrict__ kh, const unsigned short* __restrict__ kl,
    const unsigned short* __restrict__ vT, const float* __restrict__ Drec,
    const float* __restrict__ x, unsigned short* __restrict__ y) {
  const int bid = blockIdx.x, b = bid & 7, n0 = (bid >> 3) * 128;
  const int tid = threadIdx.x, w = tid >> 6, lane = tid & 63, lq = lane & 15,
            quad = lane >> 4;
  const int nq = w & 3, ch = w >> 2;
  __shared__ __align__(16) unsigned short kbuf[2][128 * 64];
  __shared__ __align__(16) unsigned short vbuf[2][CT * 64];
  __shared__ __align__(16) unsigned short Pb[128 * 64];
  __shared__ float DrecS[ND];
  __shared__ float Sb[128];
  for (int i = tid; i < ND / 4; i += 512)
    *(float4*)&DrecS[i * 4] = *(const float4*)&Drec[(size_t)b * ND + i * 4];
  short8v aq[2][2][2];
#pragma unroll
  for (int s = 0; s < 2; ++s)
#pragma unroll
    for (int k = 0; k < 2; ++k) {
      size_t a = ((size_t)b * ND + n0 + nq * 32 + s * 16 + lq) * DA + k * 32 + quad * 8;
      aq[s][k][0] = *(const short8v*)(qh + a);
      aq[s][k][1] = *(const short8v*)(ql + a);
    }
  float4v O[2][9];
#pragma unroll
  for (int s = 0; s < 2; ++s)
#pragma unroll
    for (int t = 0; t < 9; ++t) O[s][t] = (float4v){0.f, 0.f, 0.f, 0.f};

  uint4 sk0, sk1, sv[5];
  const int srow = tid >> 3, sc8 = tid & 7;
  auto load_stage = [&](int mb) {
    sk0 = *(const uint4*)(kh + ((size_t)b * ND + mb + srow) * DA + sc8 * 8);
    sk1 = *(const uint4*)(kl + ((size_t)b * ND + mb + srow) * DA + sc8 * 8);
#pragma unroll
    for (int j = 0; j < 4; ++j) {
      int c = tid + j * 512;
      sv[j] = *(const uint4*)(vT + ((size_t)b * CT + (c >> 3)) * ND + mb + (c & 7) * 8);
    }
    if (tid < 128) {
      int c = 2048 + tid;
      sv[4] = *(const uint4*)(vT + ((size_t)b * CT + (c >> 3)) * ND + mb + (c & 7) * 8);
    }
  };
  auto write_stage = [&](int buf) {
    *(uint4*)&kbuf[buf][sw(srow, sc8)] = sk0;
    *(uint4*)&kbuf[buf][sw(64 + srow, sc8)] = sk1;
#pragma unroll
    for (int j = 0; j < 4; ++j) {
      int c = tid + j * 512;
      *(uint4*)&vbuf[buf][sw(c >> 3, c & 7)] = sv[j];
    }
    if (tid < 128) {
      int c = 2048 + tid;
      *(uint4*)&vbuf[buf][sw(c >> 3, c & 7)] = sv[4];
    }
  };
  load_stage(0); write_stage(0); load_stage(64);
  __syncthreads();

#pragma unroll 1
  for (int i = 0; i < 64; ++i) {
    const int cur = i & 1, m0 = i * 64;
    // ---- e-phase: e[nq-strip][ch m-half] -> P (bf16 in LDS) ----
#pragma unroll
    for (int sub = 0; sub < 2; ++sub) {
      short8v bh[2], bl[2];
#pragma unroll
      for (int k = 0; k < 2; ++k) {
        bh[k] = *(const short8v*)&kbuf[cur][sw(ch * 32 + sub * 16 + lq, k * 4 + quad)];
        bl[k] = *(const short8v*)&kbuf[cur][sw(64 + ch * 32 + sub * 16 + lq, k * 4 + quad)];
      }
      const int m_loc = ch * 32 + sub * 16 + lq;
      const float dr = DrecS[m0 + m_loc];
#pragma unroll
      for (int s = 0; s < 2; ++s) {
        float4v acc = {0.f, 0.f, 0.f, 0.f};
#pragma unroll
        for (int k = 0; k < 2; ++k) {
          acc = mfma16(aq[s][k][0], bh[k], acc);
          acc = mfma16(aq[s][k][1], bh[k], acc);
          acc = mfma16(aq[s][k][0], bl[k], acc);
        }
        const int nrow = nq * 32 + s * 16 + quad * 4;
#pragma unroll
        for (int r = 0; r < 4; ++r) {
          float p = __expf(acc[r]) * dr;
          const int n_loc = nrow + r;
          Pb[n_loc * 64 + ((((m_loc >> 3) ^ (n_loc & 7)) << 3) | (m_loc & 7))] = f2bf(p);
        }
      }
    }
    if (i < 63) { write_stage(1 - cur); if (i < 62) load_stage((i + 2) * 64); }
    __syncthreads();
    // ---- PV-phase ----
    short8v ap[2][2];
#pragma unroll
    for (int s = 0; s < 2; ++s)
#pragma unroll
      for (int k = 0; k < 2; ++k)
        ap[s][k] = *(const short8v*)&Pb[sw(nq * 32 + s * 16 + lq, k * 4 + quad)];
    const int tbase = ch * 9;
#pragma unroll
    for (int ti = 0; ti < 8; ++ti) {
      const int t = tbase + ti;
#pragma unroll
      for (int k = 0; k < 2; ++k) {
        short8v bv = *(const short8v*)&vbuf[cur][sw(t * 16 + lq, k * 4 + quad)];
#pragma unroll
        for (int s = 0; s < 2; ++s) O[s][ti] = mfma16(ap[s][k], bv, O[s][ti]);
      }
    }
    if (ch == 0) {  // 9th tile (t=8) for ch0 only
#pragma unroll
      for (int k = 0; k < 2; ++k) {
        short8v bv = *(const short8v*)&vbuf[cur][sw(8 * 16 + lq, k * 4 + quad)];
#pragma unroll
        for (int s = 0; s < 2; ++s) O[s][8] = mfma16(ap[s][k], bv, O[s][8]);
      }
    }
    __syncthreads();
  }
  // ---- epilogue: S from ones-column (t=16 == ti 7 of ch1), y = x - O/S ----
  if (ch == 1 && lq == 0) {
#pragma unroll
    for (int s = 0; s < 2; ++s)
#pragma unroll
      for (int r = 0; r < 4; ++r)
        Sb[nq * 32 + s * 16 + quad * 4 + r] = O[s][7][r];
  }
  __syncthreads();
  float rsc[2][4];
#pragma unroll
  for (int s = 0; s < 2; ++s)
#pragma unroll
    for (int r = 0; r < 4; ++r)
      rsc[s][r] = 1.0f / (1e-9f + Sb[nq * 32 + s * 16 + quad * 4 + r]);
  // COMPILE-TIME trip count (9) + runtime guard: O[s][ti] stays constant-indexed
  // in every unrolled copy -> no scratch demotion.
#pragma unroll
  for (int ti = 0; ti < 9; ++ti) {
    const bool active = (ch == 0) || (ti < 7);
    if (active) {
      const int c = (ch * 9 + ti) * 16 + lq;
#pragma unroll
      for (int s = 0; s < 2; ++s)
#pragma unroll
        for (int r = 0; r < 4; ++r) {
          const int n = n0 + nq * 32 + s * 16 + quad * 4 + r;
          float xv = x[((size_t)(b * CD + c)) * ND + n];
          y[((size_t)b * ND + n) * CD + c] = f2bf(xv - O[s][ti][r] * rsc[s][r]);
        }
    }
  }
}

// ---------------------------------------------------------------------------
// k_final: h = Wp . y (bf16 MFMA); out = relu(BN(h)) + x.
// ---------------------------------------------------------------------------
__global__ __launch_bounds__(256) void k_final(const unsigned short* __restrict__ y,
                                               const unsigned short* __restrict__ Wpb,
                                               const float* __restrict__ x,
                                               const float* __restrict__ gamma,
                                               const float* __restrict__ beta,
                                               const float* __restrict__ mean,
                                               const float* __restrict__ var,
                                               float* __restrict__ out) {
  const int bid = blockIdx.x;
  const int b = bid & 7;
  const int rem = bid >> 3;
  const int n0 = (rem & 63) * 64;
  const int d0 = (rem >> 6) * 64;
  const int tid = threadIdx.x;
  const int wave = tid >> 6, lane = tid & 63, lq = lane & 15, quad = lane >> 4;
  const int dw = d0 + wave * 16;
  float4v O[4];
#pragma unroll
  for (int s = 0; s < 4; ++s) O[s] = (float4v){0.f, 0.f, 0.f, 0.f};
#pragma unroll
  for (int chh = 0; chh < 8; ++chh) {
    const size_t ab = (size_t)(dw + lq) * CD + chh * 32 + quad * 8;
    short8v a0 = *(const short8v*)(Wpb + ab);
#pragma unroll
    for (int s = 0; s < 4; ++s) {
      const size_t bb = ((size_t)b * ND + n0 + s * 16 + lq) * CD + chh * 32 + quad * 8;
      short8v bv = *(const short8v*)(y + bb);
      O[s] = mfma16(a0, bv, O[s]);
    }
  }
#pragma unroll
  for (int r = 0; r < 4; ++r) {
    const int d = dw + quad * 4 + r;
    const float inv  = gamma[d] / sqrtf(var[d] + 1e-5f);
    const float bias = beta[d] - mean[d] * inv;
#pragma unroll
    for (int s = 0; s < 4; ++s) {
      const int n = n0 + s * 16 + lq;
      const size_t oi = ((size_t)b * CD + d) * ND + n;
      out[oi] = fmaxf(O[s][r] * inv + bias, 0.f) + x[oi];
    }
  }
}

extern "C" void kernel_launch(void* const* d_in, const int* in_sizes, int n_in,
                              void* d_out, int out_size, void* d_ws, size_t ws_size,
                              hipStream_t stream) {
  const float* x     = (const float*)d_in[0];
  const float* Wq    = (const float*)d_in[1];
  const float* Wk    = (const float*)d_in[2];
  const float* Wv    = (const float*)d_in[3];
  const float* Wp    = (const float*)d_in[4];
  const float* gamma = (const float*)d_in[5];
  const float* beta  = (const float*)d_in[6];
  const float* mean  = (const float*)d_in[7];
  const float* var   = (const float*)d_in[8];
  float* out = (float*)d_out;

  char* wsp = (char*)d_ws;
  unsigned short* qh  = (unsigned short*)wsp; wsp += (size_t)BD * ND * DA * 2;
  unsigned short* ql  = (unsigned short*)wsp; wsp += (size_t)BD * ND * DA * 2;
  unsigned short* khp = (unsigned short*)wsp; wsp += (size_t)BD * ND * DA * 2;
  unsigned short* klp = (unsigned short*)wsp; wsp += (size_t)BD * ND * DA * 2;
  unsigned short* vT  = (unsigned short*)wsp; wsp += (size_t)BD * CT * ND * 2;
  unsigned short* xTh = (unsigned short*)wsp; wsp += (size_t)BD * ND * CD * 2;  // aliased as y
  unsigned short* xTl = (unsigned short*)wsp; wsp += (size_t)BD * ND * CD * 2;
  unsigned short* Wqh = (unsigned short*)wsp; wsp += (size_t)64 * 256 * 2;
  unsigned short* Wql = (unsigned short*)wsp; wsp += (size_t)64 * 256 * 2;
  unsigned short* Wkh = (unsigned short*)wsp; wsp += (size_t)64 * 256 * 2;
  unsigned short* Wkl = (unsigned short*)wsp; wsp += (size_t)64 * 256 * 2;
  unsigned short* Wvh = (unsigned short*)wsp; wsp += (size_t)256 * 256 * 2;
  unsigned short* Wvl = (unsigned short*)wsp; wsp += (size_t)256 * 256 * 2;
  unsigned short* Wph = (unsigned short*)wsp; wsp += (size_t)256 * 256 * 2;
  unsigned short* Wpl = (unsigned short*)wsp; wsp += (size_t)256 * 256 * 2;
  float* Drec = (float*)wsp; wsp += (size_t)BD * ND * 4;
  unsigned short* y = xTh;  // alias: xTh dead after projections

  dim3 blk(256), blk5(512);
  k_prep<<<dim3(ND / 64, CD / 64, BD), blk, 0, stream>>>(x, xTh, xTl);
  k_prepW<<<dim3(160), blk, 0, stream>>>(Wq, Wk, Wv, Wp, Wqh, Wql, Wkh, Wkl,
                                         Wvh, Wvl, Wph, Wpl);
  k_proj64<<<dim3(ND / 128, BD), blk, 0, stream>>>(xTh, xTl, Wqh, Wql, qh, ql);
  k_proj64<<<dim3(ND / 128, BD), blk, 0, stream>>>(xTh, xTl, Wkh, Wkl, khp, klp);
  k_projvT<<<dim3(ND / 128, 4, BD), blk, 0, stream>>>(xTh, xTl, Wvh, Wvl, vT);
  k_fill<<<dim3(512), blk, 0, stream>>>(vT);
  k_colsum<<<dim3(256), blk5, 0, stream>>>(qh, ql, khp, klp, Drec);
  k_attn<<<dim3(256), blk5, 0, stream>>>(qh, ql, khp, klp, vT, Drec, x, y);
  k_final<<<dim3(2048), blk, 0, stream>>>(y, Wph, x, gamma, beta, mean, var, out);
}

// Round 5
// 519.858 us; speedup vs baseline: 3.9261x; 1.0246x over previous
//
#include <hip/hip_runtime.h>
#include <math.h>

#define BD 8
#define CD 256
#define ND 4096
#define DA 64
#define CT 272  // c-tiles staged: 0..255 data, 256 = ones row, 257..271 zero

typedef __attribute__((ext_vector_type(8))) short short8v;
typedef __attribute__((ext_vector_type(4))) float float4v;

static __device__ __forceinline__ float4v mfma16(short8v a, short8v b, float4v c) {
  return __builtin_amdgcn_mfma_f32_16x16x32_bf16(a, b, c, 0, 0, 0);
}
static __device__ __forceinline__ unsigned short f2bf(float f) {
  union { float f; unsigned int u; } v; v.f = f;
  return (unsigned short)((v.u + 0x7fffu + ((v.u >> 16) & 1u)) >> 16);
}
static __device__ __forceinline__ float bf2f(unsigned short h) {
  union { unsigned int u; float f; } v; v.u = (unsigned int)h << 16;
  return v.f;
}
// XOR-swizzled LDS offset (ushort units). Rows are 64 bf16 = 128 B = 8 chunks
// of 16 B. chunk' = chunk ^ (row&7) spreads frag reads across all 32 banks.
static __device__ __forceinline__ int sw(int row, int c8) {
  return row * 64 + (((c8) ^ (row & 7)) << 3);
}
// async global->LDS 16B copy: per-lane global src, wave-uniform LDS base
// (HW adds lane*16). Swizzle must be baked into the SOURCE address.
typedef const __attribute__((address_space(1))) unsigned int g_u32;
typedef __attribute__((address_space(3))) unsigned int l_u32;
static __device__ __forceinline__ void gld16(const void* g, void* l) {
  __builtin_amdgcn_global_load_lds((g_u32*)g, (l_u32*)l, 16, 0, 0);
}

// ---------------------------------------------------------------------------
// k_prep: x [b][c][n] fp32 -> xTh/xTl [b][n][256] split bf16 (transposed).
// ---------------------------------------------------------------------------
__global__ __launch_bounds__(256) void k_prep(const float* __restrict__ x,
                                              unsigned short* __restrict__ xTh,
                                              unsigned short* __restrict__ xTl) {
  const int n0 = blockIdx.x * 64, c0 = blockIdx.y * 64, b = blockIdx.z;
  __shared__ float Xs[64][68];
  const int tid = threadIdx.x;
  const int r0 = tid >> 4, col4 = (tid & 15) * 4;
#pragma unroll
  for (int j = 0; j < 4; ++j) {
    int r = r0 + j * 16;
    *(float4*)&Xs[r][col4] =
        *(const float4*)&x[((size_t)(b * CD + c0 + r)) * ND + n0 + col4];
  }
  __syncthreads();
  const int n = tid >> 2, cg = (tid & 3) * 16;
  unsigned short h[16], l[16];
#pragma unroll
  for (int j = 0; j < 16; ++j) {
    float v = Xs[cg + j][n];
    h[j] = f2bf(v);
    l[j] = f2bf(v - bf2f(h[j]));
  }
  size_t o = ((size_t)b * ND + n0 + n) * CD + c0 + cg;
#pragma unroll
  for (int j = 0; j < 4; ++j) {
    *(ushort4*)&xTh[o + j * 4] = *(ushort4*)&h[j * 4];
    *(ushort4*)&xTl[o + j * 4] = *(ushort4*)&l[j * 4];
  }
}

// ---------------------------------------------------------------------------
// k_prepW: split Wq/Wk/Wv/Wp fp32 -> bf16 hi/lo. grid 160 x 256.
// ---------------------------------------------------------------------------
__global__ void k_prepW(const float* __restrict__ Wq, const float* __restrict__ Wk,
                        const float* __restrict__ Wv, const float* __restrict__ Wp,
                        unsigned short* Wqh, unsigned short* Wql,
                        unsigned short* Wkh, unsigned short* Wkl,
                        unsigned short* Wvh, unsigned short* Wvl,
                        unsigned short* Wph, unsigned short* Wpl) {
  int i = blockIdx.x * 256 + threadIdx.x;  // 40960 float4s over 640 rows
  int row = i >> 6, c4 = (i & 63) * 4;
  const float* src; unsigned short *dh, *dl; int r;
  if (row < 64)       { src = Wq; dh = Wqh; dl = Wql; r = row; }
  else if (row < 128) { src = Wk; dh = Wkh; dl = Wkl; r = row - 64; }
  else if (row < 384) { src = Wv; dh = Wvh; dl = Wvl; r = row - 128; }
  else                { src = Wp; dh = Wph; dl = Wpl; r = row - 384; }
  float4 f = *(const float4*)&src[(size_t)r * 256 + c4];
  ushort4 hh, ll;
  hh.x = f2bf(f.x); hh.y = f2bf(f.y); hh.z = f2bf(f.z); hh.w = f2bf(f.w);
  ll.x = f2bf(f.x - bf2f(hh.x)); ll.y = f2bf(f.y - bf2f(hh.y));
  ll.z = f2bf(f.z - bf2f(hh.z)); ll.w = f2bf(f.w - bf2f(hh.w));
  *(ushort4*)&dh[(size_t)r * 256 + c4] = hh;
  *(ushort4*)&dl[(size_t)r * 256 + c4] = ll;
}

// ---------------------------------------------------------------------------
// k_proj64: out[n][64] (split hi/lo) = xT[n][c] . W[d][c], 3-product MFMA.
// grid (32 n-tiles of 128, B), block 256 (4 waves).
// ---------------------------------------------------------------------------
__global__ __launch_bounds__(256, 4) void k_proj64(
    const unsigned short* __restrict__ xTh, const unsigned short* __restrict__ xTl,
    const unsigned short* __restrict__ Wh, const unsigned short* __restrict__ Wl,
    unsigned short* __restrict__ oh, unsigned short* __restrict__ ol) {
  const int n0 = blockIdx.x * 128, b = blockIdx.y;
  const int tid = threadIdx.x, w = tid >> 6, lane = tid & 63, lq = lane & 15,
            quad = lane >> 4;
  const int nh = w & 1, dh = w >> 1;
  float4v O[2][4];
#pragma unroll
  for (int dt = 0; dt < 2; ++dt)
#pragma unroll
    for (int nt = 0; nt < 4; ++nt) O[dt][nt] = (float4v){0.f, 0.f, 0.f, 0.f};
#pragma unroll 2
  for (int ks = 0; ks < 8; ++ks) {
    short8v awh[2], awl[2], bxh[4], bxl[4];
#pragma unroll
    for (int dt = 0; dt < 2; ++dt) {
      size_t a = (size_t)(dh * 32 + dt * 16 + lq) * CD + ks * 32 + quad * 8;
      awh[dt] = *(const short8v*)(Wh + a);
      awl[dt] = *(const short8v*)(Wl + a);
    }
#pragma unroll
    for (int nt = 0; nt < 4; ++nt) {
      size_t a = ((size_t)b * ND + n0 + nh * 64 + nt * 16 + lq) * CD + ks * 32 + quad * 8;
      bxh[nt] = *(const short8v*)(xTh + a);
      bxl[nt] = *(const short8v*)(xTl + a);
    }
#pragma unroll
    for (int dt = 0; dt < 2; ++dt)
#pragma unroll
      for (int nt = 0; nt < 4; ++nt) {
        O[dt][nt] = mfma16(awh[dt], bxh[nt], O[dt][nt]);
        O[dt][nt] = mfma16(awl[dt], bxh[nt], O[dt][nt]);
        O[dt][nt] = mfma16(awh[dt], bxl[nt], O[dt][nt]);
      }
  }
#pragma unroll
  for (int dt = 0; dt < 2; ++dt)
#pragma unroll
    for (int nt = 0; nt < 4; ++nt) {
      int d0v = dh * 32 + dt * 16 + quad * 4;
      int n = n0 + nh * 64 + nt * 16 + lq;
      ushort4 hh, ll;
      float v0 = O[dt][nt][0], v1 = O[dt][nt][1], v2 = O[dt][nt][2], v3 = O[dt][nt][3];
      hh.x = f2bf(v0); hh.y = f2bf(v1); hh.z = f2bf(v2); hh.w = f2bf(v3);
      ll.x = f2bf(v0 - bf2f(hh.x)); ll.y = f2bf(v1 - bf2f(hh.y));
      ll.z = f2bf(v2 - bf2f(hh.z)); ll.w = f2bf(v3 - bf2f(hh.w));
      size_t o = ((size_t)b * ND + n) * DA + d0v;
      *(ushort4*)&oh[o] = hh;
      *(ushort4*)&ol[o] = ll;
    }
}

// ---------------------------------------------------------------------------
// k_projvT: vT[c_out][m] bf16 = xT[m][c] . Wv[c_out][c], 3-product MFMA.
// grid (32 m-tiles of 128, 4 c_out-tiles of 64, B), block 256.
// ---------------------------------------------------------------------------
__global__ __launch_bounds__(256, 4) void k_projvT(
    const unsigned short* __restrict__ xTh, const unsigned short* __restrict__ xTl,
    const unsigned short* __restrict__ Wvh, const unsigned short* __restrict__ Wvl,
    unsigned short* __restrict__ vT) {
  const int m0 = blockIdx.x * 128, cob = blockIdx.y * 64, b = blockIdx.z;
  const int tid = threadIdx.x, w = tid >> 6, lane = tid & 63, lq = lane & 15,
            quad = lane >> 4;
  const int mh = w & 1, ch2 = w >> 1;
  float4v O[2][4];
#pragma unroll
  for (int ct = 0; ct < 2; ++ct)
#pragma unroll
    for (int mt = 0; mt < 4; ++mt) O[ct][mt] = (float4v){0.f, 0.f, 0.f, 0.f};
#pragma unroll 2
  for (int ks = 0; ks < 8; ++ks) {
    short8v awh[2], awl[2], bxh[4], bxl[4];
#pragma unroll
    for (int ct = 0; ct < 2; ++ct) {
      size_t a = (size_t)(cob + ch2 * 32 + ct * 16 + lq) * CD + ks * 32 + quad * 8;
      awh[ct] = *(const short8v*)(Wvh + a);
      awl[ct] = *(const short8v*)(Wvl + a);
    }
#pragma unroll
    for (int mt = 0; mt < 4; ++mt) {
      size_t a = ((size_t)b * ND + m0 + mh * 64 + mt * 16 + lq) * CD + ks * 32 + quad * 8;
      bxh[mt] = *(const short8v*)(xTh + a);
      bxl[mt] = *(const short8v*)(xTl + a);
    }
#pragma unroll
    for (int ct = 0; ct < 2; ++ct)
#pragma unroll
      for (int mt = 0; mt < 4; ++mt) {
        O[ct][mt] = mfma16(awh[ct], bxh[mt], O[ct][mt]);
        O[ct][mt] = mfma16(awl[ct], bxh[mt], O[ct][mt]);
        O[ct][mt] = mfma16(awh[ct], bxl[mt], O[ct][mt]);
      }
  }
#pragma unroll
  for (int ct = 0; ct < 2; ++ct)
#pragma unroll
    for (int mt = 0; mt < 4; ++mt) {
      int m = m0 + mh * 64 + mt * 16 + lq;
#pragma unroll
      for (int r = 0; r < 4; ++r) {
        int co = cob + ch2 * 32 + ct * 16 + quad * 4 + r;
        vT[((size_t)b * CT + co) * ND + m] = f2bf(O[ct][mt][r]);
      }
    }
}

// fill vT rows 256..271 (row 256 = 1.0, rest 0). 512 blocks x 256.
__global__ void k_fill(unsigned short* __restrict__ vT) {
  int i = blockIdx.x * 256 + threadIdx.x;
  int b = i >> 14, r = (i >> 10) & 15, n4 = i & 1023;
  unsigned short val = (r == 0) ? (unsigned short)0x3F80 : (unsigned short)0;
  ushort4 v; v.x = val; v.y = val; v.z = val; v.w = val;
  *(ushort4*)&vT[((size_t)b * CT + 256 + r) * ND + n4 * 4] = v;
}

// ---------------------------------------------------------------------------
// k_colsum: partial column sums of exp(e). n-split grid 512 (2 blocks/CU via
// launch_bounds (512,4) -> VGPR<=128). Block owns 128 m-cols, 2048 n-rows.
// Dp[half][b][m] = sum_{n in half} exp(e[n][m]).
// ---------------------------------------------------------------------------
__global__ __launch_bounds__(512, 4) void k_colsum(
    const unsigned short* __restrict__ qh, const unsigned short* __restrict__ ql,
    const unsigned short* __restrict__ kh, const unsigned short* __restrict__ kl,
    float* __restrict__ Dp) {
  const int bid = blockIdx.x, b = bid & 7, half = (bid >> 3) & 1,
            m0 = (bid >> 4) * 128;
  const int nbase = half * 2048;
  const int tid = threadIdx.x, w = tid >> 6, lane = tid & 63, lq = lane & 15,
            quad = lane >> 4;
  const int mq = w & 3, nh = w >> 2;
  __shared__ __align__(16) unsigned short qbuf[2][128 * 64];
  __shared__ float Cb[128];
  short8v bkh[2][2], bkl[2][2];
#pragma unroll
  for (int sub = 0; sub < 2; ++sub)
#pragma unroll
    for (int k = 0; k < 2; ++k) {
      size_t a = ((size_t)b * ND + m0 + mq * 32 + sub * 16 + lq) * DA + k * 32 + quad * 8;
      bkh[sub][k] = *(const short8v*)(kh + a);
      bkl[sub][k] = *(const short8v*)(kl + a);
    }
  uint4 sreg[2];
  const int srow = tid >> 3, sc8 = tid & 7;
  auto load_stage = [&](int nb) {
    sreg[0] = *(const uint4*)(qh + ((size_t)b * ND + nb + srow) * DA + sc8 * 8);
    sreg[1] = *(const uint4*)(ql + ((size_t)b * ND + nb + srow) * DA + sc8 * 8);
  };
  auto write_stage = [&](int buf) {
    *(uint4*)&qbuf[buf][sw(srow, sc8)] = sreg[0];
    *(uint4*)&qbuf[buf][sw(64 + srow, sc8)] = sreg[1];
  };
  load_stage(nbase); write_stage(0); load_stage(nbase + 64);
  __syncthreads();
  float cs0 = 0.f, cs1 = 0.f;
  for (int i = 0; i < 32; ++i) {
    const int cur = i & 1;
#pragma unroll
    for (int s = 0; s < 2; ++s) {
      short8v ah[2], al[2];
#pragma unroll
      for (int k = 0; k < 2; ++k) {
        ah[k] = *(const short8v*)&qbuf[cur][sw(nh * 32 + s * 16 + lq, k * 4 + quad)];
        al[k] = *(const short8v*)&qbuf[cur][sw(64 + nh * 32 + s * 16 + lq, k * 4 + quad)];
      }
#pragma unroll
      for (int sub = 0; sub < 2; ++sub) {
        float4v acc = {0.f, 0.f, 0.f, 0.f};
#pragma unroll
        for (int k = 0; k < 2; ++k) {
          acc = mfma16(ah[k], bkh[sub][k], acc);
          acc = mfma16(al[k], bkh[sub][k], acc);
          acc = mfma16(ah[k], bkl[sub][k], acc);
        }
        float e0 = __expf(acc[0]) + __expf(acc[1]) + __expf(acc[2]) + __expf(acc[3]);
        if (sub == 0) cs0 += e0; else cs1 += e0;
      }
    }
    if (i < 31) { write_stage(1 - cur); if (i < 30) load_stage(nbase + (i + 2) * 64); }
    __syncthreads();
  }
  cs0 += __shfl_down(cs0, 16); cs0 += __shfl_down(cs0, 32);
  cs1 += __shfl_down(cs1, 16); cs1 += __shfl_down(cs1, 32);
  if (nh == 0 && lane < 16) {
    Cb[mq * 32 + lane] = cs0;
    Cb[mq * 32 + 16 + lane] = cs1;
  }
  __syncthreads();
  if (nh == 1 && lane < 16) {
    float t0 = Cb[mq * 32 + lane] + cs0;
    float t1 = Cb[mq * 32 + 16 + lane] + cs1;
    size_t o = (size_t)half * (BD * ND) + (size_t)b * ND + m0 + mq * 32 + lane;
    Dp[o] = t0;
    Dp[o + 16] = t1;
  }
}

// combine halves: Drec = 1/(Dp0+Dp1). grid 32 x 256.
__global__ void k_rcp(const float* __restrict__ Dp, float* __restrict__ Drec) {
  int i = blockIdx.x * 256 + threadIdx.x;  // 8192 float4s
  float4 a = *(const float4*)&Dp[(size_t)i * 4];
  float4 c = *(const float4*)&Dp[(size_t)(BD * ND) + (size_t)i * 4];
  float4 r;
  r.x = 1.f / (a.x + c.x); r.y = 1.f / (a.y + c.y);
  r.z = 1.f / (a.z + c.z); r.w = 1.f / (a.w + c.w);
  *(float4*)&Drec[(size_t)i * 4] = r;
}

// ---------------------------------------------------------------------------
// k_attn: flash main loop, ONE barrier per iter.
// Block 512 thr = 8 waves, BQ=128, BM=64, grid 256.
//  - vT triple-buffered in LDS via global_load_lds (async DMA; swizzle baked
//    into source addresses; lane-linear dest). 3 buffers make the single
//    barrier race-free: DMA(i+1) vs PV(i-1) use different buffers and
//    PV(i) < barrier(i+1) < DMA(i+3).
//  - k B-frags straight from L2 to registers, prefetched one iter ahead.
//  - Pb double-buffered; e(i) writes Pb[i&1], PV(i) reads it after barrier.
//  - PV operands SWAPPED (A=v, B=P): D[c][n] -> epilogue lane owns 4
//    consecutive c at fixed n -> coalesced ushort4 stores; x read from
//    xTh+xTl (exact to 2^-17) and y overwrites xTh in place.
// NOTE: all accumulator loops compile-time unrolled, constant O indices
// (runtime trip counts demote O[][] to scratch -> R3: 2.9 GB HBM writes).
// ---------------------------------------------------------------------------
__global__ __launch_bounds__(512, 2) void k_attn(
    const unsigned short* __restrict__ qh, const unsigned short* __restrict__ ql,
    const unsigned short* __restrict__ khp, const unsigned short* __restrict__ klp,
    const unsigned short* __restrict__ vT, const float* __restrict__ Drec,
    unsigned short* xhy, const unsigned short* __restrict__ xTl) {
  const int bid = blockIdx.x, b = bid & 7, n0 = (bid >> 3) * 128;
  const int tid = threadIdx.x, w = tid >> 6, lane = tid & 63, lq = lane & 15,
            quad = lane >> 4;
  const int nq = w & 3, ch = w >> 2;
  __shared__ __align__(16) unsigned short vbuf[3][CT * 64];  // 104448 B
  __shared__ __align__(16) unsigned short Pb[2][128 * 64];   // 32768 B
  __shared__ float DrecS[ND];                                // 16384 B
  __shared__ float Sb[128];

  // q A-frags, resident
  short8v aq[2][2][2];
#pragma unroll
  for (int s = 0; s < 2; ++s)
#pragma unroll
    for (int k = 0; k < 2; ++k) {
      size_t a = ((size_t)b * ND + n0 + nq * 32 + s * 16 + lq) * DA + k * 32 + quad * 8;
      aq[s][k][0] = *(const short8v*)(qh + a);
      aq[s][k][1] = *(const short8v*)(ql + a);
    }
  float4v O[2][9];
#pragma unroll
  for (int s = 0; s < 2; ++s)
#pragma unroll
    for (int t = 0; t < 9; ++t) O[s][t] = (float4v){0.f, 0.f, 0.f, 0.f};

  // async vT staging: LDS chunk cidx=(row,ckpos) gets global chunk ckpos^(row&7)
  auto stageV = [&](int mt, int vn) {
    unsigned short* base = &vbuf[vn][0];
#pragma unroll
    for (int j = 0; j < 4; ++j) {
      int cidx = tid + j * 512;
      int row = cidx >> 3, ckpos = cidx & 7;
      const unsigned short* src =
          vT + ((size_t)b * CT + row) * ND + mt * 64 + ((ckpos ^ (row & 7)) << 3);
      gld16(src, base + (size_t)(w * 64 + j * 512) * 8);
    }
    if (tid < 128) {
      int cidx = 2048 + tid;
      int row = cidx >> 3, ckpos = cidx & 7;
      const unsigned short* src =
          vT + ((size_t)b * CT + row) * ND + mt * 64 + ((ckpos ^ (row & 7)) << 3);
      gld16(src, base + (size_t)(2048 + w * 64) * 8);
    }
  };
  // k B-frag loads (L2-resident), kreg idx = sub*4 + k*2 + (0=hi,1=lo)
  short8v kc[8], kn[8];
  auto kload = [&](short8v* dst, int mt) {
#pragma unroll
    for (int sub = 0; sub < 2; ++sub)
#pragma unroll
      for (int k = 0; k < 2; ++k) {
        size_t a = ((size_t)b * ND + mt * 64 + ch * 32 + sub * 16 + lq) * DA +
                   k * 32 + quad * 8;
        dst[sub * 4 + k * 2 + 0] = *(const short8v*)(khp + a);
        dst[sub * 4 + k * 2 + 1] = *(const short8v*)(klp + a);
      }
  };

  stageV(0, 0);
  kload(kc, 0);
  for (int idx = tid; idx < ND / 4; idx += 512)
    *(float4*)&DrecS[idx * 4] = *(const float4*)&Drec[(size_t)b * ND + idx * 4];
  __syncthreads();  // DrecS ready; DMA(0) drained

  int vn = 0;
#pragma unroll 1
  for (int i = 0; i < 64; ++i) {
    int vnext = vn + 1; if (vnext == 3) vnext = 0;
    if (i < 63) { stageV(i + 1, vnext); kload(kn, i + 1); }
    // ---- e(i): 3-product split-bf16 QK^T -> P (truncated bf16) in Pb[i&1]
    unsigned short* Pcur = &Pb[i & 1][0];
#pragma unroll
    for (int sub = 0; sub < 2; ++sub) {
      const int m_loc = ch * 32 + sub * 16 + lq;
      const float dr = DrecS[(i << 6) + m_loc];
#pragma unroll
      for (int s = 0; s < 2; ++s) {
        float4v acc = {0.f, 0.f, 0.f, 0.f};
#pragma unroll
        for (int k = 0; k < 2; ++k) {
          acc = mfma16(aq[s][k][0], kc[sub * 4 + k * 2 + 0], acc);
          acc = mfma16(aq[s][k][1], kc[sub * 4 + k * 2 + 0], acc);
          acc = mfma16(aq[s][k][0], kc[sub * 4 + k * 2 + 1], acc);
        }
        const int nrow = nq * 32 + s * 16 + quad * 4;
#pragma unroll
        for (int r = 0; r < 4; ++r) {
          float p = __expf(acc[r]) * dr;
          const int n_loc = nrow + r;
          union { float f; unsigned int u; } pu; pu.f = p;
          Pcur[n_loc * 64 + ((((m_loc >> 3) ^ (n_loc & 7)) << 3) | (m_loc & 7))] =
              (unsigned short)(pu.u >> 16);  // truncation: bias cancels in P/S
        }
      }
    }
    __syncthreads();  // Pb[i&1] complete; vbuf[vn] DMA (issued iter i-1) drained
    // ---- PV(i): O[c][n] += vT * P  (A=v rows c, B=P rows n)
    const unsigned short* Pc = &Pb[i & 1][0];
    const unsigned short* vc = &vbuf[vn][0];
    short8v ap[2][2];
#pragma unroll
    for (int s = 0; s < 2; ++s)
#pragma unroll
      for (int k = 0; k < 2; ++k)
        ap[s][k] = *(const short8v*)&Pc[sw(nq * 32 + s * 16 + lq, k * 4 + quad)];
#pragma unroll
    for (int ti = 0; ti < 9; ++ti) {
      if (ch == 0 || ti < 8) {
        const int t = ch * 9 + ti;
#pragma unroll
        for (int k = 0; k < 2; ++k) {
          short8v bv = *(const short8v*)&vc[sw(t * 16 + lq, k * 4 + quad)];
#pragma unroll
          for (int s = 0; s < 2; ++s) O[s][ti] = mfma16(bv, ap[s][k], O[s][ti]);
        }
      }
    }
    if (i < 63) {
#pragma unroll
      for (int t = 0; t < 8; ++t) kc[t] = kn[t];
    }
    vn = vnext;
  }
  // ---- epilogue: S from ones-row (t=16 -> ch1 ti=7, c-row 0 -> quad0 reg0)
  if (ch == 1 && quad == 0) {
#pragma unroll
    for (int s = 0; s < 2; ++s) Sb[nq * 32 + s * 16 + lq] = O[s][7][0];
  }
  __syncthreads();
  float rsc[2];
#pragma unroll
  for (int s = 0; s < 2; ++s)
    rsc[s] = 1.0f / (1e-9f + Sb[nq * 32 + s * 16 + lq]);
  // y = x - O/S, written in place over xTh (disjoint (n,c) per lane)
#pragma unroll
  for (int ti = 0; ti < 9; ++ti) {
    const bool active = (ch == 0) || (ti < 7);
    if (active) {
      const int t = ch * 9 + ti;
      const int cb = t * 16 + quad * 4;
#pragma unroll
      for (int s = 0; s < 2; ++s) {
        const int n = n0 + nq * 32 + s * 16 + lq;
        const size_t off = ((size_t)b * ND + n) * CD + cb;
        ushort4 h4 = *(const ushort4*)&xhy[off];
        ushort4 l4 = *(const ushort4*)&xTl[off];
        ushort4 o4;
        o4.x = f2bf(bf2f(h4.x) + bf2f(l4.x) - O[s][ti][0] * rsc[s]);
        o4.y = f2bf(bf2f(h4.y) + bf2f(l4.y) - O[s][ti][1] * rsc[s]);
        o4.z = f2bf(bf2f(h4.z) + bf2f(l4.z) - O[s][ti][2] * rsc[s]);
        o4.w = f2bf(bf2f(h4.w) + bf2f(l4.w) - O[s][ti][3] * rsc[s]);
        *(ushort4*)&xhy[off] = o4;
      }
    }
  }
}

// ---------------------------------------------------------------------------
// k_final: h = Wp . y (bf16 MFMA); out = relu(BN(h)) + x.
// ---------------------------------------------------------------------------
__global__ __launch_bounds__(256) void k_final(const unsigned short* __restrict__ y,
                                               const unsigned short* __restrict__ Wpb,
                                               const float* __restrict__ x,
                                               const float* __restrict__ gamma,
                                               const float* __restrict__ beta,
                                               const float* __restrict__ mean,
                                               const float* __restrict__ var,
                                               float* __restrict__ out) {
  const int bid = blockIdx.x;
  const int b = bid & 7;
  const int rem = bid >> 3;
  const int n0 = (rem & 63) * 64;
  const int d0 = (rem >> 6) * 64;
  const int tid = threadIdx.x;
  const int wave = tid >> 6, lane = tid & 63, lq = lane & 15, quad = lane >> 4;
  const int dw = d0 + wave * 16;
  float4v O[4];
#pragma unroll
  for (int s = 0; s < 4; ++s) O[s] = (float4v){0.f, 0.f, 0.f, 0.f};
#pragma unroll
  for (int chh = 0; chh < 8; ++chh) {
    const size_t ab = (size_t)(dw + lq) * CD + chh * 32 + quad * 8;
    short8v a0 = *(const short8v*)(Wpb + ab);
#pragma unroll
    for (int s = 0; s < 4; ++s) {
      const size_t bb = ((size_t)b * ND + n0 + s * 16 + lq) * CD + chh * 32 + quad * 8;
      short8v bv = *(const short8v*)(y + bb);
      O[s] = mfma16(a0, bv, O[s]);
    }
  }
#pragma unroll
  for (int r = 0; r < 4; ++r) {
    const int d = dw + quad * 4 + r;
    const float inv  = gamma[d] / sqrtf(var[d] + 1e-5f);
    const float bias = beta[d] - mean[d] * inv;
#pragma unroll
    for (int s = 0; s < 4; ++s) {
      const int n = n0 + s * 16 + lq;
      const size_t oi = ((size_t)b * CD + d) * ND + n;
      out[oi] = fmaxf(O[s][r] * inv + bias, 0.f) + x[oi];
    }
  }
}

extern "C" void kernel_launch(void* const* d_in, const int* in_sizes, int n_in,
                              void* d_out, int out_size, void* d_ws, size_t ws_size,
                              hipStream_t stream) {
  const float* x     = (const float*)d_in[0];
  const float* Wq    = (const float*)d_in[1];
  const float* Wk    = (const float*)d_in[2];
  const float* Wv    = (const float*)d_in[3];
  const float* Wp    = (const float*)d_in[4];
  const float* gamma = (const float*)d_in[5];
  const float* beta  = (const float*)d_in[6];
  const float* mean  = (const float*)d_in[7];
  const float* var   = (const float*)d_in[8];
  float* out = (float*)d_out;

  char* wsp = (char*)d_ws;
  unsigned short* qh  = (unsigned short*)wsp; wsp += (size_t)BD * ND * DA * 2;
  unsigned short* ql  = (unsigned short*)wsp; wsp += (size_t)BD * ND * DA * 2;
  unsigned short* khp = (unsigned short*)wsp; wsp += (size_t)BD * ND * DA * 2;
  unsigned short* klp = (unsigned short*)wsp; wsp += (size_t)BD * ND * DA * 2;
  unsigned short* vT  = (unsigned short*)wsp; wsp += (size_t)BD * CT * ND * 2;
  unsigned short* xTh = (unsigned short*)wsp; wsp += (size_t)BD * ND * CD * 2;  // aliased as y
  unsigned short* xTl = (unsigned short*)wsp; wsp += (size_t)BD * ND * CD * 2;
  unsigned short* Wqh = (unsigned short*)wsp; wsp += (size_t)64 * 256 * 2;
  unsigned short* Wql = (unsigned short*)wsp; wsp += (size_t)64 * 256 * 2;
  unsigned short* Wkh = (unsigned short*)wsp; wsp += (size_t)64 * 256 * 2;
  unsigned short* Wkl = (unsigned short*)wsp; wsp += (size_t)64 * 256 * 2;
  unsigned short* Wvh = (unsigned short*)wsp; wsp += (size_t)256 * 256 * 2;
  unsigned short* Wvl = (unsigned short*)wsp; wsp += (size_t)256 * 256 * 2;
  unsigned short* Wph = (unsigned short*)wsp; wsp += (size_t)256 * 256 * 2;
  unsigned short* Wpl = (unsigned short*)wsp; wsp += (size_t)256 * 256 * 2;
  float* Drec = (float*)wsp; wsp += (size_t)BD * ND * 4;
  float* Dp   = (float*)wsp; wsp += (size_t)2 * BD * ND * 4;
  unsigned short* y = xTh;  // alias: xTh consumed+overwritten by k_attn epilogue

  dim3 blk(256), blk5(512);
  k_prep<<<dim3(ND / 64, CD / 64, BD), blk, 0, stream>>>(x, xTh, xTl);
  k_prepW<<<dim3(160), blk, 0, stream>>>(Wq, Wk, Wv, Wp, Wqh, Wql, Wkh, Wkl,
                                         Wvh, Wvl, Wph, Wpl);
  k_proj64<<<dim3(ND / 128, BD), blk, 0, stream>>>(xTh, xTl, Wqh, Wql, qh, ql);
  k_proj64<<<dim3(ND / 128, BD), blk, 0, stream>>>(xTh, xTl, Wkh, Wkl, khp, klp);
  k_projvT<<<dim3(ND / 128, 4, BD), blk, 0, stream>>>(xTh, xTl, Wvh, Wvl, vT);
  k_fill<<<dim3(512), blk, 0, stream>>>(vT);
  k_colsum<<<dim3(512), blk5, 0, stream>>>(qh, ql, khp, klp, Dp);
  k_rcp<<<dim3(32), blk, 0, stream>>>(Dp, Drec);
  k_attn<<<dim3(256), blk5, 0, stream>>>(qh, ql, khp, klp, vT, Drec, y, xTl);
  k_final<<<dim3(2048), blk, 0, stream>>>(y, Wph, x, gamma, beta, mean, var, out);
}